// Round 3
// baseline (473.168 us; speedup 1.0000x reference)
//
#include <hip/hip_runtime.h>
#include <stdint.h>

// Problem constants
#define NROWS 8192
#define DIN   512
#define HIDN  1024
#define EMBN  64
#define NCONS 62      // EMB - N_EFF
#define NCLS  16
#define MARGINF 0.01f
#define MSTRIPE 2048  // rows per pipeline stripe (keeps ws footprint at 11.5 MB)

typedef unsigned short u16;
typedef __attribute__((ext_vector_type(8))) short short8;   // 8 bf16 (4 VGPRs)
typedef __attribute__((ext_vector_type(4))) float floatx4;  // 4 fp32 acc

__device__ __forceinline__ u16 f32_to_bf16(float f) {
  union { float f; uint32_t u; } x; x.f = f;
  uint32_t u = x.u;
  uint32_t r = (u + 0x7FFFu + ((u >> 16) & 1u)) >> 16;  // RNE
  return (u16)r;
}

__device__ __forceinline__ float fast_tanh(float x) {
  float xc = fminf(fmaxf(x, -10.f), 10.f);     // clamp: avoid inf/inf
  float e = __expf(2.f * xc);
  return (e - 1.f) * __builtin_amdgcn_rcpf(e + 1.f);
}

// ---------------------------------------------------------------------------
// bf16 MFMA GEMM: C[M,N] = act(A[M,K] @ B[K,N] + bias), B given TRANSPOSED
// (Bt is N x K row-major, bf16). A is M x K row-major bf16.
// BK=32 (one 16x16x32 MFMA K-step). 256 threads = 4 waves, waves 2x2.
// Verified layouts (learn_hip m89/m91/m120):
//   A-frag: A[m=lane&15][k=quad*8+j]; B-frag: B[k=quad*8+j][n=lane&15]
//   C/D:    col=lane&15, row=quad*4+reg
// Staging: global_load_lds width=16, LDS dest = wave-uniform base + lane*16.
// ---------------------------------------------------------------------------
template<int BM, int BN, bool TANH, bool WF32, bool WBF>
__global__ __launch_bounds__(256)
void gemm_bt(const u16* __restrict__ A, const u16* __restrict__ Bt,
             const float* __restrict__ bias,
             float* __restrict__ Cf, u16* __restrict__ Cbf,
             const int N, const int K)
{
  constexpr int BK = 32;
  static_assert(BM % 32 == 0 && BN % 32 == 0, "");
  __shared__ u16 lA[BM * BK];
  __shared__ u16 lB[BN * BK];

  const int tid  = threadIdx.x;
  const int wave = tid >> 6;
  const int lane = tid & 63;
  const int quad = lane >> 4;
  const int l15  = lane & 15;

  const int m0 = blockIdx.y * BM;
  const int n0 = blockIdx.x * BN;

  constexpr int SM = BM / 32;   // 16x16 subtiles per wave (m)
  constexpr int SN = BN / 32;   // 16x16 subtiles per wave (n)
  const int wm = wave >> 1;     // 0..1
  const int wn = wave & 1;      // 0..1

  constexpr int UA = BM / 16;   // staging units (16 rows x 32 k = 1KB each)
  constexpr int UB = BN / 16;
  const int srow = lane >> 2;        // 0..15 within unit
  const int scol = (lane & 3) << 3;  // 0,8,16,24

  floatx4 acc[SM][SN];
#pragma unroll
  for (int i = 0; i < SM; ++i)
#pragma unroll
    for (int j = 0; j < SN; ++j)
      acc[i][j] = (floatx4){0.f, 0.f, 0.f, 0.f};

  for (int k0 = 0; k0 < K; k0 += BK) {
    __syncthreads();   // previous iteration's LDS reads complete
    for (int u = wave; u < UA + UB; u += 4) {
      const u16* g;
      u16* l;
      if (u < UA) {
        g = A + (size_t)(m0 + u * 16 + srow) * K + (k0 + scol);
        l = lA + u * (16 * BK);
      } else {
        const int v = u - UA;
        g = Bt + (size_t)(n0 + v * 16 + srow) * K + (k0 + scol);
        l = lB + v * (16 * BK);
      }
      __builtin_amdgcn_global_load_lds(
          (const __attribute__((address_space(1))) void*)g,
          (__attribute__((address_space(3))) void*)l, 16, 0, 0);
    }
    __syncthreads();   // compiler emits vmcnt(0) drain before s_barrier

    short8 af[SM], bfr[SN];
#pragma unroll
    for (int i = 0; i < SM; ++i)
      af[i] = *(const short8*)(lA + (wm * (BM / 2) + i * 16 + l15) * BK + quad * 8);
#pragma unroll
    for (int j = 0; j < SN; ++j)
      bfr[j] = *(const short8*)(lB + (wn * (BN / 2) + j * 16 + l15) * BK + quad * 8);
#pragma unroll
    for (int i = 0; i < SM; ++i)
#pragma unroll
      for (int j = 0; j < SN; ++j)
        acc[i][j] = __builtin_amdgcn_mfma_f32_16x16x32_bf16(af[i], bfr[j], acc[i][j], 0, 0, 0);
  }

  const int mb = m0 + wm * (BM / 2);
  const int nb = n0 + wn * (BN / 2);
#pragma unroll
  for (int i = 0; i < SM; ++i) {
#pragma unroll
    for (int j = 0; j < SN; ++j) {
      const int col = nb + j * 16 + l15;
      const float bv = bias[col];
#pragma unroll
      for (int r = 0; r < 4; ++r) {
        const int row = mb + i * 16 + quad * 4 + r;
        float v = acc[i][j][r] + bv;
        if constexpr (TANH) v = fast_tanh(v);
        const size_t o = (size_t)row * N + col;
        if constexpr (WF32) Cf[o] = v;
        if constexpr (WBF)  Cbf[o] = f32_to_bf16(v);
      }
    }
  }
}

// ---------------------------------------------------------------------------
// Weight transposes (K x N fp32 -> N x K bf16), LDS 32x32 tiles; block 0 also
// zeroes the accumulator slab (runs before any atomics use it).
// ---------------------------------------------------------------------------
__global__ __launch_bounds__(256)
void prep_weights(const float* __restrict__ W1, const float* __restrict__ W4,
                  const float* __restrict__ W2, const float* __restrict__ W3,
                  u16* __restrict__ W1T, u16* __restrict__ W4T,
                  u16* __restrict__ W2T, u16* __restrict__ W3T,
                  float* __restrict__ accz, int accz_words)
{
  const int b = blockIdx.x;
  if (b == 0) {
    for (int i = threadIdx.x; i < accz_words; i += 256) accz[i] = 0.f;
  }
  const float* in; u16* out; int K, N, t;
  if (b < 512)       { in = W1; out = W1T; K = 512;  N = 1024; t = b; }
  else if (b < 1024) { in = W4; out = W4T; K = 1024; N = 512;  t = b - 512; }
  else if (b < 1088) { in = W2; out = W2T; K = 1024; N = 64;   t = b - 1024; }
  else               { in = W3; out = W3T; K = 64;   N = 1024; t = b - 1088; }
  const int tiles_n = N >> 5;
  const int tk = t / tiles_n, tn = t % tiles_n;

  __shared__ float tile[32][33];
  const int r = threadIdx.x >> 5, c = threadIdx.x & 31;
  for (int rr = r; rr < 32; rr += 8)
    tile[rr][c] = in[(size_t)(tk * 32 + rr) * N + (tn * 32 + c)];
  __syncthreads();
  for (int rr = r; rr < 32; rr += 8)
    out[(size_t)(tn * 32 + rr) * K + (tk * 32 + c)] = f32_to_bf16(tile[c][rr]);
}

// labels + class histogram (8192 threads)
__global__ __launch_bounds__(256)
void labels_kernel(const float* __restrict__ x, int* __restrict__ labels,
                   int* __restrict__ counts)
{
  const int g = blockIdx.x * 256 + threadIdx.x;
  if (g < NROWS) {
    const int l = (int)x[(size_t)g * 513];
    labels[g] = l;
    atomicAdd(&counts[l], 1);
  }
}

// One M-stripe of x (rows only, col 0 skipped) -> bf16 A-stripe
__global__ __launch_bounds__(256)
void conv_stripe(const float* __restrict__ xs, u16* __restrict__ A0s)
{
  const int g = blockIdx.x * 256 + threadIdx.x;
  const int T = 1024 * 256;
  for (int e = g; e < MSTRIPE * DIN; e += T) {
    const int i = e >> 9, k = e & 511;
    A0s[e] = f32_to_bf16(xs[(size_t)i * 513 + 1 + k]);
  }
}

__global__ void make_offsets(const int* __restrict__ counts,
                             int* __restrict__ offs, int* __restrict__ cursors)
{
  if (threadIdx.x == 0) {
    int s = 0;
    for (int c = 0; c < NCLS; ++c) { offs[c] = s; cursors[c] = s; s += counts[c]; }
    offs[NCLS] = s;
  }
}

__global__ __launch_bounds__(256)
void scatter_idx(const int* __restrict__ labels, int* __restrict__ cursors,
                 int* __restrict__ idx)
{
  const int i = blockIdx.x * 256 + threadIdx.x;
  if (i < NROWS) {
    const int c = labels[i];
    const int p = atomicAdd(&cursors[c], 1);
    idx[p] = i;
  }
}

// Per-row squared norm of conserved dims (cols 2..63) from fp32 embedding.
__global__ __launch_bounds__(256)
void sqrow_kernel(const float* __restrict__ Ef, float* __restrict__ sqrow)
{
  const int row = blockIdx.x * 256 + threadIdx.x;
  const float4* p = (const float4*)(Ef + (size_t)row * EMBN);
  float s = 0.f;
#pragma unroll
  for (int c = 0; c < 16; ++c) {
    float4 v = p[c];
    if (c == 0) { v.x = 0.f; v.y = 0.f; }
    s += v.x * v.x + v.y * v.y + v.z * v.z + v.w * v.w;
  }
  sqrow[row] = s;
}

// Atomic-free per-class stats via idx grouping: one block per class.
// vsum[c][k-2] = sum of conserved col k over class rows; Ssum[c] = sum sqrow.
__global__ __launch_bounds__(256)
void stats2(const float* __restrict__ Ef, const float* __restrict__ sqrow,
            const int* __restrict__ idx, const int* __restrict__ offs,
            float* __restrict__ vsum, float* __restrict__ Ssum)
{
  const int cls = blockIdx.x;
  const int start = offs[cls];
  const int n = offs[cls + 1] - start;
  const int tid = threadIdx.x;
  const int k = tid & 63, rg = tid >> 6;

  float v = 0.f;
  for (int r = rg; r < n; r += 4)
    v += Ef[(size_t)idx[start + r] * EMBN + k];   // wave reads one row: coalesced

  float s = 0.f;
  for (int r = tid; r < n; r += 256) s += sqrow[idx[start + r]];

  __shared__ float lv[4][64];
  __shared__ float lsq[256];
  lv[rg][k] = v;
  lsq[tid] = s;
  __syncthreads();
  if (tid < 64 && tid >= 2)
    vsum[cls * NCONS + tid - 2] = lv[0][tid] + lv[1][tid] + lv[2][tid] + lv[3][tid];
  for (int st = 128; st > 0; st >>= 1) {
    if (tid < st) lsq[tid] += lsq[tid + st];
    __syncthreads();
  }
  if (tid == 0) Ssum[cls] = lsq[0];
}

// ---------------------------------------------------------------------------
// Same-class pairwise hinge via bf16 MFMA gram: D_ij = (sq_i+sq_j-2 c_i.c_j)/62
// hinge = max(0, margin - D). Off-diagonal D ~ 2 >> margin, so bf16-gram error
// cannot produce material hinge contributions; diagonal added analytically in
// finalize. Triangular tile grid (ti<=tj), weight 2 off-diag.
// ---------------------------------------------------------------------------
__global__ __launch_bounds__(256)
void pairwise_mfma(const u16* __restrict__ Ebf, const float* __restrict__ sqrow,
                   const int* __restrict__ idx, const int* __restrict__ offs,
                   float* __restrict__ pair_sum)
{
  const int cls = blockIdx.y;
  int p = blockIdx.x, ti = 0, cnt = 16;
  while (p >= cnt) { p -= cnt; ++ti; --cnt; }   // block-uniform scalar decode
  const int tj = ti + p;

  const int start = offs[cls];
  const int n = offs[cls + 1] - start;
  if (ti * 64 >= n || tj * 64 >= n) return;

  constexpr int LDA = 72;   // pad: 2-way bank aliasing only (free)
  __shared__ u16 Li[64 * LDA];
  __shared__ u16 Lj[64 * LDA];
  __shared__ float sqI[64], sqJ[64];

  const int tid = threadIdx.x;
  for (int e = tid; e < 1024; e += 256) {
    const int t = e >> 9;
    const int row = (e >> 3) & 63;
    const int ch = e & 7;
    const int g = (t ? tj : ti) * 64 + row;
    short8 v = (short8)0;
    if (g < n) {
      v = *(const short8*)(Ebf + (size_t)idx[start + g] * EMBN + ch * 8);
      if (ch == 0) { v[0] = 0; v[1] = 0; }
    }
    *(short8*)((t ? Lj : Li) + row * LDA + ch * 8) = v;
  }
  if (tid < 128) {
    const int t = tid >> 6, row = tid & 63;
    const int g = (t ? tj : ti) * 64 + row;
    (t ? sqJ : sqI)[row] = (g < n) ? sqrow[idx[start + g]] : 0.f;
  }
  __syncthreads();

  const int wave = tid >> 6, lane = tid & 63;
  const int wm = wave >> 1, wn = wave & 1;
  const int quad = lane >> 4, l15 = lane & 15;

  floatx4 acc[2][2];
#pragma unroll
  for (int i = 0; i < 2; ++i)
#pragma unroll
    for (int j = 0; j < 2; ++j) acc[i][j] = (floatx4){0.f, 0.f, 0.f, 0.f};

#pragma unroll
  for (int ks = 0; ks < 2; ++ks) {
    short8 af[2], bf[2];
#pragma unroll
    for (int i = 0; i < 2; ++i)
      af[i] = *(const short8*)(Li + (wm * 32 + i * 16 + l15) * LDA + ks * 32 + quad * 8);
#pragma unroll
    for (int j = 0; j < 2; ++j)
      bf[j] = *(const short8*)(Lj + (wn * 32 + j * 16 + l15) * LDA + ks * 32 + quad * 8);
#pragma unroll
    for (int i = 0; i < 2; ++i)
#pragma unroll
      for (int j = 0; j < 2; ++j)
        acc[i][j] = __builtin_amdgcn_mfma_f32_16x16x32_bf16(af[i], bf[j], acc[i][j], 0, 0, 0);
  }

  float local = 0.f;
#pragma unroll
  for (int i = 0; i < 2; ++i)
#pragma unroll
    for (int j = 0; j < 2; ++j)
#pragma unroll
      for (int r = 0; r < 4; ++r) {
        const int row = wm * 32 + i * 16 + quad * 4 + r;
        const int col = wn * 32 + j * 16 + l15;
        const int gi = ti * 64 + row, gj = tj * 64 + col;
        if (gi < n && gj < n && gi != gj) {
          const float D = (sqI[row] + sqJ[col] - 2.f * acc[i][j][r]) * (1.f / 62.f);
          local += fmaxf(0.f, MARGINF - D);
        }
      }
  if (ti < tj) local *= 2.f;

  __shared__ float red[256];
  red[tid] = local;
  __syncthreads();
  for (int st = 128; st > 0; st >>= 1) {
    if (tid < st) red[tid] += red[tid + st];
    __syncthreads();
  }
  if (tid == 0) atomicAdd(pair_sum, red[0]);
}

__device__ __forceinline__ double block_reduce_d(double v, double* red, int tid) {
  red[tid] = v;
  __syncthreads();
  for (int st = 128; st > 0; st >>= 1) {
    if (tid < st) red[tid] += red[tid + st];
    __syncthreads();
  }
  const double r = red[0];
  __syncthreads();
  return r;
}

// C_sim (factored, no N^2) and C_diff from pair_sum + analytic diagonal.
__global__ __launch_bounds__(256)
void finalize(const float* __restrict__ vsum, const float* __restrict__ Ssum,
              const int* __restrict__ counts, const float* __restrict__ pair_sum,
              float* __restrict__ out2)
{
  const int tid = threadIdx.x;
  __shared__ double red[256];

  double v = 0.0;
  if (tid < NCLS) v = (double)Ssum[tid] * (double)(NROWS - counts[tid]);
  const double t1 = block_reduce_d(v, red, tid);            // sum_c S_c (N - n_c)

  v = 0.0;
  if (tid < NCLS) { const double nc = (double)counts[tid]; v = nc * nc; }
  const double n_same = block_reduce_d(v, red, tid);        // sum n_c^2

  v = 0.0;
  for (int i = tid; i < NCLS * NCONS; i += 256) { const double w = vsum[i]; v += w * w; }
  const double t2 = block_reduce_d(v, red, tid);            // sum_c |v_c|^2

  v = 0.0;
  if (tid < NCONS) {
    double Vk = 0.0;
    for (int c = 0; c < NCLS; ++c) Vk += (double)vsum[c * NCONS + tid];
    v = Vk * Vk;
  }
  const double t3 = block_reduce_d(v, red, tid);            // |V|^2

  if (tid == 0) {
    const double n_diff = (double)NROWS * (double)NROWS - n_same;
    const double sim = 2.0 * t1 - 2.0 * (t3 - t2);
    const double C_sim = sim / 62.0 / (n_diff + 1.0);
    const double C_diff = ((double)pair_sum[0] + (double)NROWS * (double)MARGINF)
                          / (n_same + 1.0);
    out2[0] = (float)C_sim;
    out2[1] = (float)C_diff;
  }
}

// ---------------------------------------------------------------------------
// Workspace footprint: 11.5 MB total (was 30 MB — suspected OOB past ws_size
// corrupting the harness's pristine input copies: launch_once passed, every
// post-restore call diverged O(1)). MLP is striped over M in 4 chunks of 2048
// rows; A-stripe (2 MB) and H/T-stripe (4 MB) are reused across stripes.
// ---------------------------------------------------------------------------
extern "C" void kernel_launch(void* const* d_in, const int* in_sizes, int n_in,
                              void* d_out, int out_size, void* d_ws, size_t ws_size,
                              hipStream_t stream)
{
  const float* x  = (const float*)d_in[0];
  const float* W1 = (const float*)d_in[1];
  const float* b1 = (const float*)d_in[2];
  const float* W2 = (const float*)d_in[3];
  const float* b2 = (const float*)d_in[4];
  const float* W3 = (const float*)d_in[5];
  const float* b3 = (const float*)d_in[6];
  const float* W4 = (const float*)d_in[7];
  const float* b4 = (const float*)d_in[8];
  float* out = (float*)d_out;

  char* ws = (char*)d_ws;
  const size_t KB = 1024, MB = 1ull << 20;
  u16* W1T    = (u16*)(ws + 0);                    // 1 MB  (1024 x 512)
  u16* W4T    = (u16*)(ws + 1 * MB);               // 1 MB  (512 x 1024)
  u16* W2T    = (u16*)(ws + 2 * MB);               // 128 KB (64 x 1024)
  u16* W3T    = (u16*)(ws + 2 * MB + 128 * KB);    // 128 KB (1024 x 64)
  int* labels = (int*)(ws + 2 * MB + 256 * KB);    // 32 KB
  int* idx    = (int*)(ws + 2 * MB + 288 * KB);    // 32 KB
  float* acc  = (float*)(ws + 2 * MB + 320 * KB);  // 16 KB slab
  int*   counts  = (int*)acc;                      // [0,16)
  int*   offs    = counts + 16;                    // [16,33)
  int*   cursors = counts + 64;                    // [64,80)
  float* Ssum    = (float*)(counts + 96);          // 16
  float* psum    = (float*)(counts + 128);         // 1
  float* vsum    = (float*)(counts + 256);         // 992
  float* sqrow = (float*)(ws + 2 * MB + 384 * KB); // 32 KB (8192 f32)
  float* Ef   = (float*)(ws + 2 * MB + 512 * KB);  // 2 MB  (8192 x 64 f32)
  u16* Ebf    = (u16*)(ws + 4 * MB + 512 * KB);    // 1 MB  (8192 x 64 bf16)
  u16* A0s    = (u16*)(ws + 5 * MB + 512 * KB);    // 2 MB  (2048 x 512 bf16)
  u16* Hs     = (u16*)(ws + 7 * MB + 512 * KB);    // 4 MB  (2048 x 1024); reused as T
  (void)in_sizes; (void)n_in; (void)out_size; (void)ws_size;

  prep_weights<<<dim3(1152), dim3(256), 0, stream>>>(W1, W4, W2, W3,
                                                     W1T, W4T, W2T, W3T, acc, 2048);
  labels_kernel<<<dim3(32), dim3(256), 0, stream>>>(x, labels, counts);
  make_offsets<<<dim3(1), dim3(64), 0, stream>>>(counts, offs, cursors);
  scatter_idx<<<dim3(32), dim3(256), 0, stream>>>(labels, cursors, idx);

  for (int s = 0; s < NROWS / MSTRIPE; ++s) {
    const float* xs = x + (size_t)s * MSTRIPE * 513;
    const size_t oE = (size_t)s * MSTRIPE * EMBN;
    const size_t oO = (size_t)s * MSTRIPE * DIN;

    conv_stripe<<<dim3(1024), dim3(256), 0, stream>>>(xs, A0s);
    // Hs = tanh(A0s @ W1 + b1)        M=2048 N=1024 K=512
    gemm_bt<128, 64, true, false, true><<<dim3(16, 16), dim3(256), 0, stream>>>(
        A0s, W1T, b1, (float*)nullptr, Hs, 1024, 512);
    // E-stripe = Hs @ W2 + b2         M=2048 N=64 K=1024 (f32 + bf16 out)
    gemm_bt<64, 64, false, true, true><<<dim3(1, 32), dim3(256), 0, stream>>>(
        Hs, W2T, b2, Ef + oE, Ebf + oE, 64, 1024);
    // Ts = tanh(E-stripe @ W3 + b3)   M=2048 N=1024 K=64 (overwrites Hs)
    gemm_bt<128, 64, true, false, true><<<dim3(16, 16), dim3(256), 0, stream>>>(
        Ebf + oE, W3T, b3, (float*)nullptr, Hs, 1024, 64);
    // decoded-stripe = Ts @ W4 + b4   M=2048 N=512 K=1024 (f32 -> d_out)
    gemm_bt<128, 64, false, true, false><<<dim3(8, 16), dim3(256), 0, stream>>>(
        Hs, W4T, b4, out + oO, (u16*)nullptr, 512, 1024);
  }

  sqrow_kernel<<<dim3(32), dim3(256), 0, stream>>>(Ef, sqrow);
  stats2<<<dim3(16), dim3(256), 0, stream>>>(Ef, sqrow, idx, offs, vsum, Ssum);
  pairwise_mfma<<<dim3(136, 16), dim3(256), 0, stream>>>(Ebf, sqrow, idx, offs, psum);
  finalize<<<dim3(1), dim3(256), 0, stream>>>(vsum, Ssum, counts, psum,
                                              out + (size_t)NROWS * DIN);
}

// Round 4
// 292.930 us; speedup vs baseline: 1.6153x; 1.6153x over previous
//
#include <hip/hip_runtime.h>
#include <stdint.h>

// Problem constants
#define NROWS 8192
#define DIN   512
#define HIDN  1024
#define EMBN  64
#define NCONS 62      // EMB - N_EFF
#define NCLS  16
#define MARGINF 0.01f

typedef unsigned short u16;
typedef __attribute__((ext_vector_type(8))) short short8;   // 8 bf16 (4 VGPRs)
typedef __attribute__((ext_vector_type(4))) float floatx4;  // 4 fp32 acc

__device__ __forceinline__ u16 f32_to_bf16(float f) {
  union { float f; uint32_t u; } x; x.f = f;
  uint32_t u = x.u;
  uint32_t r = (u + 0x7FFFu + ((u >> 16) & 1u)) >> 16;  // RNE
  return (u16)r;
}

__device__ __forceinline__ float bf16_to_f32(u16 h) {
  union { uint32_t u; float f; } x; x.u = (uint32_t)h << 16;
  return x.f;
}

__device__ __forceinline__ float fast_tanh(float x) {
  float xc = fminf(fmaxf(x, -10.f), 10.f);     // clamp: avoid inf/inf
  float e = __expf(2.f * xc);
  return (e - 1.f) * __builtin_amdgcn_rcpf(e + 1.f);
}

__device__ __forceinline__ void load_lds16(const u16* g, u16* l) {
  __builtin_amdgcn_global_load_lds(
      (const __attribute__((address_space(1))) void*)g,
      (__attribute__((address_space(3))) void*)l, 16, 0, 0);
}

// ---------------------------------------------------------------------------
// Fused layer1+layer2: per block 32 rows of x.
//   Ea (LDS, bf16, pad 520) <- x rows (fp32->bf16, col 0 skipped)
//   for each of 16 HID-chunks (64 cols):
//     Hc = tanh(Ea @ W1T-chunk + b1)   [K=512, staged 128-k rounds of BK=32]
//     Hc -> LDS (C-layout write, pad 72), then used as A-operand
//     Eacc += Hc @ W2T-chunk           [K=64]
//   Ebf = bf16(Eacc + b2)
// MFMA layouts per learn_hip m89/m91/m120 (verified):
//   A-frag A[m=lane&15][k=quad*8+j]; B-frag B[k=quad*8+j][n=lane&15]
//   C/D: col=lane&15, row=quad*4+reg
// H (8192x1024, 32 MB of traffic in the unfused version) never leaves the CU.
// ---------------------------------------------------------------------------
__global__ __launch_bounds__(256)
void gemm12(const float* __restrict__ x, const u16* __restrict__ W1T,
            const float* __restrict__ b1, const u16* __restrict__ W2T,
            const float* __restrict__ b2, u16* __restrict__ Ebf)
{
  constexpr int PEA = 520;  // Ea row pitch (u16): 2-way bank alias only
  constexpr int PH  = 72;   // Hc row pitch
  __shared__ u16 Ea[32 * PEA];       // 33.3 KB
  __shared__ u16 lB[4 * 64 * 32];    // 16 KB: 4 k-units of W1T chunk
  __shared__ u16 lW2[2 * 64 * 32];   // 8 KB: 2 k-units of W2T chunk
  __shared__ u16 Hc[32 * PH];        // 4.6 KB

  const int tid  = threadIdx.x;
  const int wave = tid >> 6;
  const int lane = tid & 63;
  const int quad = lane >> 4;
  const int l15  = lane & 15;
  const int wm = wave >> 1;          // 2x2 wave grid
  const int wn = wave & 1;
  const int srow = lane >> 2;        // staging: 16 rows x 32k unit
  const int scol = (lane & 3) << 3;

  const int m0 = blockIdx.x * 32;

  // ---- stage x rows -> Ea (bf16) ----
  for (int e = tid; e < 32 * 512; e += 256) {
    const int row = e >> 9, k = e & 511;
    Ea[row * PEA + k] = f32_to_bf16(x[(size_t)(m0 + row) * 513 + 1 + k]);
  }

  floatx4 Eacc[2];
  Eacc[0] = (floatx4){0.f, 0.f, 0.f, 0.f};
  Eacc[1] = (floatx4){0.f, 0.f, 0.f, 0.f};

  for (int c = 0; c < 16; ++c) {     // HID chunk: cols c*64 .. c*64+63
    floatx4 Hacc[2];
    Hacc[0] = (floatx4){0.f, 0.f, 0.f, 0.f};
    Hacc[1] = (floatx4){0.f, 0.f, 0.f, 0.f};

    for (int r4 = 0; r4 < 4; ++r4) {         // 128-k staging round
      __syncthreads();
      for (int s = wave; s < 16; s += 4) {   // 4 units x 4 row-groups
        const int u = s >> 2, i = s & 3;
        load_lds16(W1T + (size_t)(c * 64 + i * 16 + srow) * 512
                       + r4 * 128 + u * 32 + scol,
                   lB + u * 2048 + (i * 16 + srow) * 32 + scol);
      }
      __syncthreads();
#pragma unroll
      for (int kk = 0; kk < 4; ++kk) {
        const short8 af = *(const short8*)(Ea + (wm * 16 + l15) * PEA
                                              + r4 * 128 + kk * 32 + quad * 8);
#pragma unroll
        for (int j = 0; j < 2; ++j) {
          const short8 bf = *(const short8*)(lB + kk * 2048
                                + (wn * 32 + j * 16 + l15) * 32 + quad * 8);
          Hacc[j] = __builtin_amdgcn_mfma_f32_16x16x32_bf16(af, bf, Hacc[j], 0, 0, 0);
        }
      }
    }

    // tanh + write Hc (C-layout) ; stage W2T chunk concurrently
#pragma unroll
    for (int j = 0; j < 2; ++j) {
      const int col = wn * 32 + j * 16 + l15;
      const float bv = b1[c * 64 + col];
#pragma unroll
      for (int r = 0; r < 4; ++r) {
        const int row = wm * 16 + quad * 4 + r;
        Hc[row * PH + col] = f32_to_bf16(fast_tanh(Hacc[j][r] + bv));
      }
    }
    for (int s = wave; s < 8; s += 4) {      // 2 units x 4 row-groups
      const int u = s >> 2, i = s & 3;
      load_lds16(W2T + (size_t)(i * 16 + srow) * 1024 + c * 64 + u * 32 + scol,
                 lW2 + u * 2048 + (i * 16 + srow) * 32 + scol);
    }
    __syncthreads();

#pragma unroll
    for (int kk = 0; kk < 2; ++kk) {
      const short8 af = *(const short8*)(Hc + (wm * 16 + l15) * PH
                                            + kk * 32 + quad * 8);
#pragma unroll
      for (int j = 0; j < 2; ++j) {
        const short8 bf = *(const short8*)(lW2 + kk * 2048
                              + (wn * 32 + j * 16 + l15) * 32 + quad * 8);
        Eacc[j] = __builtin_amdgcn_mfma_f32_16x16x32_bf16(af, bf, Eacc[j], 0, 0, 0);
      }
    }
    __syncthreads();   // protect Hc/lW2/lB before next chunk overwrites
  }

#pragma unroll
  for (int j = 0; j < 2; ++j) {
    const int col = wn * 32 + j * 16 + l15;
    const float bv = b2[col];
#pragma unroll
    for (int r = 0; r < 4; ++r) {
      const int row = wm * 16 + quad * 4 + r;
      Ebf[(size_t)(m0 + row) * 64 + col] = f32_to_bf16(Eacc[j][r] + bv);
    }
  }
}

// ---------------------------------------------------------------------------
// Fused layer3+layer4: block = 32 rows x 128 decoded cols.
//   Et (LDS) <- Ebf tile (full 64 cols)
//   for each of 16 HID-chunks: Tc = tanh(Et @ W3T-chunk + b3) [K=64]
//                              Dacc += Tc @ W4T-chunk          [K=64]
//   out = Dacc + b4 (fp32)
// T (8192x1024) never leaves the CU; T recomputed per N-block (x4, +4.3 GF).
// ---------------------------------------------------------------------------
__global__ __launch_bounds__(256)
void gemm34(const u16* __restrict__ Ebf, const u16* __restrict__ W3T,
            const float* __restrict__ b3, const u16* __restrict__ W4T,
            const float* __restrict__ b4, float* __restrict__ out)
{
  constexpr int PH = 72;
  __shared__ u16 Et[32 * PH];         // 4.6 KB
  __shared__ u16 Tc[32 * PH];         // 4.6 KB
  __shared__ u16 lB[2 * 64 * 32];     // 8 KB  (W3T chunk)
  __shared__ u16 lW4[2 * 128 * 32];   // 16 KB (W4T chunk)

  const int tid  = threadIdx.x;
  const int wave = tid >> 6;
  const int lane = tid & 63;
  const int quad = lane >> 4;
  const int l15  = lane & 15;
  const int wm = wave >> 1;
  const int wn = wave & 1;
  const int srow = lane >> 2;
  const int scol = (lane & 3) << 3;

  const int m0 = blockIdx.y * 32;
  const int n0 = blockIdx.x * 128;

  // Et <- Ebf tile (one short8 per thread)
  {
    const int row = tid >> 3, ch = tid & 7;
    *(short8*)(Et + row * PH + ch * 8) =
        *(const short8*)(Ebf + (size_t)(m0 + row) * 64 + ch * 8);
  }

  floatx4 Dacc[4];
#pragma unroll
  for (int j = 0; j < 4; ++j) Dacc[j] = (floatx4){0.f, 0.f, 0.f, 0.f};

  for (int c = 0; c < 16; ++c) {
    __syncthreads();                       // prior chunk's reads done (+Et ready)
    for (int s = wave; s < 8; s += 4) {    // W3T chunk: 2 units x 4 groups
      const int u = s >> 2, i = s & 3;
      load_lds16(W3T + (size_t)(c * 64 + i * 16 + srow) * 64 + u * 32 + scol,
                 lB + u * 2048 + (i * 16 + srow) * 32 + scol);
    }
    __syncthreads();

    floatx4 Tacc[2];
    Tacc[0] = (floatx4){0.f, 0.f, 0.f, 0.f};
    Tacc[1] = (floatx4){0.f, 0.f, 0.f, 0.f};
#pragma unroll
    for (int kk = 0; kk < 2; ++kk) {
      const short8 af = *(const short8*)(Et + (wm * 16 + l15) * PH
                                            + kk * 32 + quad * 8);
#pragma unroll
      for (int j = 0; j < 2; ++j) {
        const short8 bf = *(const short8*)(lB + kk * 2048
                              + (wn * 32 + j * 16 + l15) * 32 + quad * 8);
        Tacc[j] = __builtin_amdgcn_mfma_f32_16x16x32_bf16(af, bf, Tacc[j], 0, 0, 0);
      }
    }
#pragma unroll
    for (int j = 0; j < 2; ++j) {
      const int col = wn * 32 + j * 16 + l15;
      const float bv = b3[c * 64 + col];
#pragma unroll
      for (int r = 0; r < 4; ++r) {
        const int row = wm * 16 + quad * 4 + r;
        Tc[row * PH + col] = f32_to_bf16(fast_tanh(Tacc[j][r] + bv));
      }
    }
    for (int s = wave; s < 16; s += 4) {   // W4T chunk: 2 units x 8 groups
      const int u = s >> 3, i = s & 7;
      load_lds16(W4T + (size_t)(n0 + i * 16 + srow) * 1024 + c * 64 + u * 32 + scol,
                 lW4 + u * 4096 + (i * 16 + srow) * 32 + scol);
    }
    __syncthreads();

#pragma unroll
    for (int kk = 0; kk < 2; ++kk) {
      const short8 af = *(const short8*)(Tc + (wm * 16 + l15) * PH
                                            + kk * 32 + quad * 8);
#pragma unroll
      for (int j = 0; j < 4; ++j) {
        const short8 bf = *(const short8*)(lW4 + kk * 4096
                              + (wn * 64 + j * 16 + l15) * 32 + quad * 8);
        Dacc[j] = __builtin_amdgcn_mfma_f32_16x16x32_bf16(af, bf, Dacc[j], 0, 0, 0);
      }
    }
  }

#pragma unroll
  for (int j = 0; j < 4; ++j) {
    const int col = n0 + wn * 64 + j * 16 + l15;
    const float bv = b4[col];
#pragma unroll
    for (int r = 0; r < 4; ++r) {
      const int row = m0 + wm * 16 + quad * 4 + r;
      out[(size_t)row * 512 + col] = Dacc[j][r] + bv;
    }
  }
}

// ---------------------------------------------------------------------------
// Weight transposes (K x N fp32 -> N x K bf16), LDS 32x32 tiles; block 0 also
// zeroes the accumulator slab (runs before any atomics use it).
// ---------------------------------------------------------------------------
__global__ __launch_bounds__(256)
void prep_weights(const float* __restrict__ W1, const float* __restrict__ W4,
                  const float* __restrict__ W2, const float* __restrict__ W3,
                  u16* __restrict__ W1T, u16* __restrict__ W4T,
                  u16* __restrict__ W2T, u16* __restrict__ W3T,
                  float* __restrict__ accz, int accz_words)
{
  const int b = blockIdx.x;
  if (b == 0) {
    for (int i = threadIdx.x; i < accz_words; i += 256) accz[i] = 0.f;
  }
  const float* in; u16* out; int K, N, t;
  if (b < 512)       { in = W1; out = W1T; K = 512;  N = 1024; t = b; }
  else if (b < 1024) { in = W4; out = W4T; K = 1024; N = 512;  t = b - 512; }
  else if (b < 1088) { in = W2; out = W2T; K = 1024; N = 64;   t = b - 1024; }
  else               { in = W3; out = W3T; K = 64;   N = 1024; t = b - 1088; }
  const int tiles_n = N >> 5;
  const int tk = t / tiles_n, tn = t % tiles_n;

  __shared__ float tile[32][33];
  const int r = threadIdx.x >> 5, c = threadIdx.x & 31;
  for (int rr = r; rr < 32; rr += 8)
    tile[rr][c] = in[(size_t)(tk * 32 + rr) * N + (tn * 32 + c)];
  __syncthreads();
  for (int rr = r; rr < 32; rr += 8)
    out[(size_t)(tn * 32 + rr) * K + (tk * 32 + c)] = f32_to_bf16(tile[c][rr]);
}

// labels + class histogram
__global__ __launch_bounds__(256)
void labels_kernel(const float* __restrict__ x, int* __restrict__ labels,
                   int* __restrict__ counts)
{
  const int g = blockIdx.x * 256 + threadIdx.x;
  if (g < NROWS) {
    const int l = (int)x[(size_t)g * 513];
    labels[g] = l;
    atomicAdd(&counts[l], 1);
  }
}

__global__ void make_offsets(const int* __restrict__ counts,
                             int* __restrict__ offs, int* __restrict__ cursors)
{
  if (threadIdx.x == 0) {
    int s = 0;
    for (int c = 0; c < NCLS; ++c) { offs[c] = s; cursors[c] = s; s += counts[c]; }
    offs[NCLS] = s;
  }
}

__global__ __launch_bounds__(256)
void scatter_idx(const int* __restrict__ labels, int* __restrict__ cursors,
                 int* __restrict__ idx)
{
  const int i = blockIdx.x * 256 + threadIdx.x;
  if (i < NROWS) {
    const int c = labels[i];
    const int p = atomicAdd(&cursors[c], 1);
    idx[p] = i;
  }
}

// ---------------------------------------------------------------------------
// Stats + per-row sq norm from Ebf, one pass. 64 blocks x 4 waves x 32 rows.
// Wave reads a full row coalesced (lane = col); cols 0,1 zeroed. Per-class LDS
// accumulators: 64 distinct addresses per wave -> no same-address serialization.
// sqrow via wave shuffle-reduce (exactly consistent with bf16 gram: diag = 0).
// ---------------------------------------------------------------------------
__global__ __launch_bounds__(256)
void stats_sq(const u16* __restrict__ Ebf, const int* __restrict__ labels,
              float* __restrict__ sqrow, float* __restrict__ vsum,
              float* __restrict__ Ssum)
{
  __shared__ float lv[NCLS][64];
  __shared__ float lsq[NCLS][64];
  const int tid = threadIdx.x;
  for (int i = tid; i < NCLS * 64; i += 256) {
    ((float*)lv)[i] = 0.f; ((float*)lsq)[i] = 0.f;
  }
  __syncthreads();

  const int wave = tid >> 6, lane = tid & 63;
  const int base = blockIdx.x * 128 + wave * 32;
  for (int r = 0; r < 32; ++r) {
    const int row = base + r;
    const int c = labels[row];                       // uniform broadcast load
    float v = bf16_to_f32(Ebf[(size_t)row * 64 + lane]);
    if (lane < 2) v = 0.f;
    const float v2 = v * v;
    atomicAdd(&lv[c][lane], v);
    atomicAdd(&lsq[c][lane], v2);
    float s = v2;
    for (int o = 32; o > 0; o >>= 1) s += __shfl_xor(s, o);
    if (lane == 0) sqrow[row] = s;
  }
  __syncthreads();

  for (int i = tid; i < NCLS * 64; i += 256) {
    const int c = i >> 6, k = i & 63;
    if (k >= 2) atomicAdd(&vsum[c * NCONS + k - 2], lv[c][k]);
  }
  if (tid < NCLS) {
    float s = 0.f;
    for (int k = 0; k < 64; ++k) s += lsq[tid][k];
    atomicAdd(&Ssum[tid], s);
  }
}

// ---------------------------------------------------------------------------
// Same-class pairwise hinge via bf16 MFMA gram (verified R2/R3 numerics).
// ---------------------------------------------------------------------------
__global__ __launch_bounds__(256)
void pairwise_mfma(const u16* __restrict__ Ebf, const float* __restrict__ sqrow,
                   const int* __restrict__ idx, const int* __restrict__ offs,
                   float* __restrict__ pair_sum)
{
  const int cls = blockIdx.y;
  int p = blockIdx.x, ti = 0, cnt = 16;
  while (p >= cnt) { p -= cnt; ++ti; --cnt; }   // block-uniform scalar decode
  const int tj = ti + p;

  const int start = offs[cls];
  const int n = offs[cls + 1] - start;
  if (ti * 64 >= n || tj * 64 >= n) return;

  constexpr int LDA = 72;
  __shared__ u16 Li[64 * LDA];
  __shared__ u16 Lj[64 * LDA];
  __shared__ float sqI[64], sqJ[64];

  const int tid = threadIdx.x;
  for (int e = tid; e < 1024; e += 256) {
    const int t = e >> 9;
    const int row = (e >> 3) & 63;
    const int ch = e & 7;
    const int g = (t ? tj : ti) * 64 + row;
    short8 v = (short8)0;
    if (g < n) {
      v = *(const short8*)(Ebf + (size_t)idx[start + g] * EMBN + ch * 8);
      if (ch == 0) { v[0] = 0; v[1] = 0; }
    }
    *(short8*)((t ? Lj : Li) + row * LDA + ch * 8) = v;
  }
  if (tid < 128) {
    const int t = tid >> 6, row = tid & 63;
    const int g = (t ? tj : ti) * 64 + row;
    (t ? sqJ : sqI)[row] = (g < n) ? sqrow[idx[start + g]] : 0.f;
  }
  __syncthreads();

  const int wave = tid >> 6, lane = tid & 63;
  const int wm = wave >> 1, wn = wave & 1;
  const int quad = lane >> 4, l15 = lane & 15;

  floatx4 acc[2][2];
#pragma unroll
  for (int i = 0; i < 2; ++i)
#pragma unroll
    for (int j = 0; j < 2; ++j) acc[i][j] = (floatx4){0.f, 0.f, 0.f, 0.f};

#pragma unroll
  for (int ks = 0; ks < 2; ++ks) {
    short8 af[2], bf[2];
#pragma unroll
    for (int i = 0; i < 2; ++i)
      af[i] = *(const short8*)(Li + (wm * 32 + i * 16 + l15) * LDA + ks * 32 + quad * 8);
#pragma unroll
    for (int j = 0; j < 2; ++j)
      bf[j] = *(const short8*)(Lj + (wn * 32 + j * 16 + l15) * LDA + ks * 32 + quad * 8);
#pragma unroll
    for (int i = 0; i < 2; ++i)
#pragma unroll
      for (int j = 0; j < 2; ++j)
        acc[i][j] = __builtin_amdgcn_mfma_f32_16x16x32_bf16(af[i], bf[j], acc[i][j], 0, 0, 0);
  }

  float local = 0.f;
#pragma unroll
  for (int i = 0; i < 2; ++i)
#pragma unroll
    for (int j = 0; j < 2; ++j)
#pragma unroll
      for (int r = 0; r < 4; ++r) {
        const int row = wm * 32 + i * 16 + quad * 4 + r;
        const int col = wn * 32 + j * 16 + l15;
        const int gi = ti * 64 + row, gj = tj * 64 + col;
        if (gi < n && gj < n && gi != gj) {
          const float D = (sqI[row] + sqJ[col] - 2.f * acc[i][j][r]) * (1.f / 62.f);
          local += fmaxf(0.f, MARGINF - D);
        }
      }
  if (ti < tj) local *= 2.f;

  __shared__ float red[256];
  red[tid] = local;
  __syncthreads();
  for (int st = 128; st > 0; st >>= 1) {
    if (tid < st) red[tid] += red[tid + st];
    __syncthreads();
  }
  if (tid == 0) atomicAdd(pair_sum, red[0]);
}

__device__ __forceinline__ double block_reduce_d(double v, double* red, int tid) {
  red[tid] = v;
  __syncthreads();
  for (int st = 128; st > 0; st >>= 1) {
    if (tid < st) red[tid] += red[tid + st];
    __syncthreads();
  }
  const double r = red[0];
  __syncthreads();
  return r;
}

// C_sim (factored, no N^2) and C_diff from pair_sum + analytic diagonal.
__global__ __launch_bounds__(256)
void finalize(const float* __restrict__ vsum, const float* __restrict__ Ssum,
              const int* __restrict__ counts, const float* __restrict__ pair_sum,
              float* __restrict__ out2)
{
  const int tid = threadIdx.x;
  __shared__ double red[256];

  double v = 0.0;
  if (tid < NCLS) v = (double)Ssum[tid] * (double)(NROWS - counts[tid]);
  const double t1 = block_reduce_d(v, red, tid);            // sum_c S_c (N - n_c)

  v = 0.0;
  if (tid < NCLS) { const double nc = (double)counts[tid]; v = nc * nc; }
  const double n_same = block_reduce_d(v, red, tid);        // sum n_c^2

  v = 0.0;
  for (int i = tid; i < NCLS * NCONS; i += 256) { const double w = vsum[i]; v += w * w; }
  const double t2 = block_reduce_d(v, red, tid);            // sum_c |v_c|^2

  v = 0.0;
  if (tid < NCONS) {
    double Vk = 0.0;
    for (int c = 0; c < NCLS; ++c) Vk += (double)vsum[c * NCONS + tid];
    v = Vk * Vk;
  }
  const double t3 = block_reduce_d(v, red, tid);            // |V|^2

  if (tid == 0) {
    const double n_diff = (double)NROWS * (double)NROWS - n_same;
    const double sim = 2.0 * t1 - 2.0 * (t3 - t2);
    const double C_sim = sim / 62.0 / (n_diff + 1.0);
    const double C_diff = ((double)pair_sum[0] + (double)NROWS * (double)MARGINF)
                          / (n_same + 1.0);
    out2[0] = (float)C_sim;
    out2[1] = (float)C_diff;
  }
}

// ---------------------------------------------------------------------------
// Workspace footprint: 3.5 MB (H and T eliminated by fusion; Ef dropped —
// stats run on Ebf). 9 dispatches total.
// ---------------------------------------------------------------------------
extern "C" void kernel_launch(void* const* d_in, const int* in_sizes, int n_in,
                              void* d_out, int out_size, void* d_ws, size_t ws_size,
                              hipStream_t stream)
{
  const float* x  = (const float*)d_in[0];
  const float* W1 = (const float*)d_in[1];
  const float* b1 = (const float*)d_in[2];
  const float* W2 = (const float*)d_in[3];
  const float* b2 = (const float*)d_in[4];
  const float* W3 = (const float*)d_in[5];
  const float* b3 = (const float*)d_in[6];
  const float* W4 = (const float*)d_in[7];
  const float* b4 = (const float*)d_in[8];
  float* out = (float*)d_out;

  char* ws = (char*)d_ws;
  const size_t KB = 1024, MB = 1ull << 20;
  u16* W1T    = (u16*)(ws + 0);                    // 1 MB  (1024 x 512)
  u16* W4T    = (u16*)(ws + 1 * MB);               // 1 MB  (512 x 1024)
  u16* W2T    = (u16*)(ws + 2 * MB);               // 128 KB (64 x 1024)
  u16* W3T    = (u16*)(ws + 2 * MB + 128 * KB);    // 128 KB (1024 x 64)
  int* labels = (int*)(ws + 2 * MB + 256 * KB);    // 32 KB
  int* idx    = (int*)(ws + 2 * MB + 288 * KB);    // 32 KB
  float* acc  = (float*)(ws + 2 * MB + 320 * KB);  // 16 KB slab (zeroed)
  int*   counts  = (int*)acc;                      // [0,16)
  int*   offs    = counts + 16;                    // [16,33)
  int*   cursors = counts + 64;                    // [64,80)
  float* Ssum    = (float*)(counts + 96);          // 16
  float* psum    = (float*)(counts + 128);         // 1
  float* vsum    = (float*)(counts + 256);         // 992
  float* sqrow = (float*)(ws + 2 * MB + 384 * KB); // 32 KB (8192 f32)
  u16* Ebf    = (u16*)(ws + 2 * MB + 512 * KB);    // 1 MB (8192 x 64 bf16)
  (void)in_sizes; (void)n_in; (void)out_size; (void)ws_size;

  prep_weights<<<dim3(1152), dim3(256), 0, stream>>>(W1, W4, W2, W3,
                                                     W1T, W4T, W2T, W3T, acc, 2048);
  labels_kernel<<<dim3(32), dim3(256), 0, stream>>>(x, labels, counts);
  make_offsets<<<dim3(1), dim3(64), 0, stream>>>(counts, offs, cursors);
  scatter_idx<<<dim3(32), dim3(256), 0, stream>>>(labels, cursors, idx);

  gemm12<<<dim3(256), dim3(256), 0, stream>>>(x, W1T, b1, W2T, b2, Ebf);
  stats_sq<<<dim3(64), dim3(256), 0, stream>>>(Ebf, labels, sqrow, vsum, Ssum);
  gemm34<<<dim3(4, 256), dim3(256), 0, stream>>>(Ebf, W3T, b3, W4T, b4, out);
  pairwise_mfma<<<dim3(136, 16), dim3(256), 0, stream>>>(Ebf, sqrow, idx, offs, psum);
  finalize<<<dim3(1), dim3(256), 0, stream>>>(vsum, Ssum, counts, psum,
                                              out + (size_t)NROWS * DIN);
}

// Round 5
// 249.083 us; speedup vs baseline: 1.8996x; 1.1760x over previous
//
#include <hip/hip_runtime.h>
#include <stdint.h>

// Problem constants
#define NROWS 8192
#define DIN   512
#define HIDN  1024
#define EMBN  64
#define NCONS 62      // EMB - N_EFF
#define NCLS  16
#define MARGINF 0.01f

typedef unsigned short u16;
typedef __attribute__((ext_vector_type(8))) short short8;   // 8 bf16 (4 VGPRs)
typedef __attribute__((ext_vector_type(4))) float floatx4;  // 4 fp32 acc

__device__ __forceinline__ u16 f32_to_bf16(float f) {
  union { float f; uint32_t u; } x; x.f = f;
  uint32_t u = x.u;
  uint32_t r = (u + 0x7FFFu + ((u >> 16) & 1u)) >> 16;  // RNE
  return (u16)r;
}

__device__ __forceinline__ float bf16_to_f32(u16 h) {
  union { uint32_t u; float f; } x; x.u = (uint32_t)h << 16;
  return x.f;
}

__device__ __forceinline__ float fast_tanh(float x) {
  float xc = fminf(fmaxf(x, -10.f), 10.f);     // clamp: avoid inf/inf
  float e = __expf(2.f * xc);
  return (e - 1.f) * __builtin_amdgcn_rcpf(e + 1.f);
}

__device__ __forceinline__ void load_lds16(const u16* g, u16* l) {
  __builtin_amdgcn_global_load_lds(
      (const __attribute__((address_space(1))) void*)g,
      (__attribute__((address_space(3))) void*)l, 16, 0, 0);
}

// ---------------------------------------------------------------------------
// Weight pre-pack: W (K x N fp32) -> 1KB tiles [nt][ku], tile = 16 n-rows x
// 32 k. Within a tile, row r's k-chunk c (8 bf16 = 16B) is stored at slot
// c ^ ((r>>1)&3) so that after global_load_lds staging (contiguous lane
// order), B-fragment reads alias banks at most 2-way (free per m136).
// Tile linear index = nt*KU + ku; chunk lane L = r*4 + slot.
// ---------------------------------------------------------------------------
__device__ __forceinline__ void pack_tile(const float* __restrict__ W,
                                          u16* __restrict__ Wp,
                                          int N, int KU, int t, int lane)
{
  const int r = lane >> 2, slot = lane & 3;
  const int c = slot ^ ((r >> 1) & 3);
  const int nt = t / KU, ku = t - nt * KU;
  const int n = nt * 16 + r;
  const int kb = ku * 32 + c * 8;
  short8 v;
#pragma unroll
  for (int j = 0; j < 8; ++j) v[j] = (short)f32_to_bf16(W[(size_t)(kb + j) * N + n]);
  *(short8*)(Wp + ((size_t)t * 64 + lane) * 8) = v;
}

// pack W1 (512x1024 -> 1024 tiles) + W2 (1024x64 -> 128 tiles); zero Ef+slab.
__global__ __launch_bounds__(256)
void pack1(const float* __restrict__ W1, const float* __restrict__ W2,
           u16* __restrict__ W1p, u16* __restrict__ W2p,
           float* __restrict__ Ef, float* __restrict__ slab)
{
  const int tid = threadIdx.x;
  for (int i = blockIdx.x * 256 + tid; i < NROWS * EMBN; i += 288 * 256) Ef[i] = 0.f;
  if (blockIdx.x == 0) for (int i = tid; i < 4096; i += 256) slab[i] = 0.f;
  const int tl = tid >> 6, lane = tid & 63;
  if (blockIdx.x < 256) pack_tile(W1, W1p, 1024, 16, blockIdx.x * 4 + tl, lane);
  else                  pack_tile(W2, W2p, 64,   32, (blockIdx.x - 256) * 4 + tl, lane);
}

// pack W4 (1024x512 -> 1024 tiles) + W3 (64x1024 -> 128 tiles); runs AFTER
// gemm12 (targets overlay the then-dead A0p region).
__global__ __launch_bounds__(256)
void pack2(const float* __restrict__ W4, const float* __restrict__ W3,
           u16* __restrict__ W4p, u16* __restrict__ W3p)
{
  const int tid = threadIdx.x;
  const int tl = tid >> 6, lane = tid & 63;
  if (blockIdx.x < 256) pack_tile(W4, W4p, 512,  32, blockIdx.x * 4 + tl, lane);
  else                  pack_tile(W3, W3p, 1024, 2,  (blockIdx.x - 256) * 4 + tl, lane);
}

// ---------------------------------------------------------------------------
// x -> A0p: bf16 A-operand pre-packed in MFMA fragment order.
// Tile (rt, ku) = 16 rows x 32 k, 1 KB; within tile lane L = quad*16+l15
// holds A[row=rt*16+l15][k=ku*32+quad*8 .. +8] (16B). A-frag load in gemm12
// is then ONE coalesced global dwordx4 per lane.
// ---------------------------------------------------------------------------
__global__ __launch_bounds__(256)
void conv_a0p(const float* __restrict__ x, u16* __restrict__ A0p)
{
  const int tid = threadIdx.x;
  const int t = blockIdx.x * 4 + (tid >> 6);     // tile id: rt*16 + ku
  const int lane = tid & 63;
  const int rt = t >> 4, ku = t & 15;
  const int r = lane & 15, q = lane >> 4;
  const float* src = x + (size_t)(rt * 16 + r) * 513 + 1 + ku * 32 + q * 8;
  short8 v;
#pragma unroll
  for (int j = 0; j < 8; ++j) v[j] = (short)f32_to_bf16(src[j]);
  *(short8*)(A0p + ((size_t)t * 64 + lane) * 8) = v;
}

// ---------------------------------------------------------------------------
// Fused layer1+layer2, HID split 4 ways. Block = 64 rows x 256 HID cols (g).
// Per K-step (BK=32, 16 steps over DIN=512): stage 16 W1p tiles -> lB; A-frags
// direct from A0p (global dwordx4); 16 MFMA/wave. Then tanh -> Hc (pitch 66),
// then E-partial = Hc @ W2p-chunk (K=256), atomicAdd into fp32 Ef (pre-zeroed;
// bias b2 added later in stats_sq). H never touches global memory.
// MFMA layouts (learn_hip m89/m91): A[m=l15][k=quad*8+j]; B[k=quad*8+j][n=l15];
// C/D col=l15, row=quad*4+reg.
// ---------------------------------------------------------------------------
__global__ __launch_bounds__(256)
void gemm12(const u16* __restrict__ A0p, const u16* __restrict__ W1p,
            const float* __restrict__ b1, const u16* __restrict__ W2p,
            float* __restrict__ Ef)
{
  __shared__ u16 lB[16 * 512];        // 16 KB: 16 B-tiles (256 cols x 32 k)
  __shared__ u16 lW2[4 * 512];        // 4 KB
  __shared__ u16 Hc[4][64 * 66];      // 33 KB: 4 chunks of 64x64, pitch 66

  const int tid  = threadIdx.x;
  const int wave = tid >> 6;
  const int lane = tid & 63;
  const int quad = lane >> 4;
  const int l15  = lane & 15;
  const int wm = wave >> 1, wn = wave & 1;
  const int xslot = (l15 >> 1) & 3;   // XOR-swizzle key for packed B reads

  const int m0 = blockIdx.x * 64;
  const int g  = blockIdx.y;          // HID group: cols g*256 .. +256

  floatx4 Hacc[4][2][2];
#pragma unroll
  for (int c = 0; c < 4; ++c)
#pragma unroll
    for (int i = 0; i < 2; ++i)
#pragma unroll
      for (int j = 0; j < 2; ++j) Hacc[c][i][j] = (floatx4){0.f, 0.f, 0.f, 0.f};

  for (int s = 0; s < 16; ++s) {      // K-steps over DIN
    __syncthreads();
#pragma unroll
    for (int u = 0; u < 4; ++u) {     // stage 16 tiles, 4 per wave
      const int jt = wave + u * 4;
      load_lds16(W1p + (size_t)((g * 16 + jt) * 16 + s) * 512 + lane * 8,
                 lB + jt * 512);
    }
    short8 af[2];
#pragma unroll
    for (int i = 0; i < 2; ++i)       // A-frags direct from global (packed)
      af[i] = *(const short8*)(A0p +
               (size_t)(((m0 >> 4) + wm * 2 + i) * 16 + s) * 512 + lane * 8);
    __syncthreads();                  // vmcnt(0) drain: lB + af ready
#pragma unroll
    for (int c = 0; c < 4; ++c)
#pragma unroll
      for (int j = 0; j < 2; ++j) {
        const short8 bf = *(const short8*)(lB + (c * 4 + wn * 2 + j) * 512
                            + l15 * 32 + ((quad ^ xslot) << 3));
#pragma unroll
        for (int i = 0; i < 2; ++i)
          Hacc[c][i][j] = __builtin_amdgcn_mfma_f32_16x16x32_bf16(af[i], bf, Hacc[c][i][j], 0, 0, 0);
      }
  }

  // tanh + Hc write (C-layout -> pitch-66 LDS)
#pragma unroll
  for (int c = 0; c < 4; ++c)
#pragma unroll
    for (int j = 0; j < 2; ++j) {
      const int col = wn * 32 + j * 16 + l15;
      const float bv = b1[g * 256 + c * 64 + col];
#pragma unroll
      for (int i = 0; i < 2; ++i)
#pragma unroll
        for (int r = 0; r < 4; ++r) {
          const int row = wm * 32 + i * 16 + quad * 4 + r;
          Hc[c][row * 66 + col] = f32_to_bf16(fast_tanh(Hacc[c][i][j][r] + bv));
        }
    }

  floatx4 Eacc[2][2];
#pragma unroll
  for (int i = 0; i < 2; ++i)
#pragma unroll
    for (int j = 0; j < 2; ++j) Eacc[i][j] = (floatx4){0.f, 0.f, 0.f, 0.f};

  for (int es = 0; es < 8; ++es) {    // E K-steps over this block's 256 HID
    if (es) __syncthreads();
    load_lds16(W2p + (size_t)(wave * 32 + g * 8 + es) * 512 + lane * 8,
               lW2 + wave * 512);     // tile nt=wave
    __syncthreads();                  // Hc visible (es=0) + lW2 ready
    const int cc = es >> 1, hh = es & 1;
    short8 af2[2];
#pragma unroll
    for (int i = 0; i < 2; ++i)
      af2[i] = *(const short8*)(Hc[cc] + (wm * 32 + i * 16 + l15) * 66
                                + hh * 32 + quad * 8);
#pragma unroll
    for (int j = 0; j < 2; ++j) {
      const short8 bf = *(const short8*)(lW2 + (wn * 2 + j) * 512
                          + l15 * 32 + ((quad ^ xslot) << 3));
#pragma unroll
      for (int i = 0; i < 2; ++i)
        Eacc[i][j] = __builtin_amdgcn_mfma_f32_16x16x32_bf16(af2[i], bf, Eacc[i][j], 0, 0, 0);
    }
  }

#pragma unroll
  for (int i = 0; i < 2; ++i)
#pragma unroll
    for (int j = 0; j < 2; ++j) {
      const int col = wn * 32 + j * 16 + l15;
#pragma unroll
      for (int r = 0; r < 4; ++r) {
        const int row = m0 + wm * 32 + i * 16 + quad * 4 + r;
        atomicAdd(&Ef[(size_t)row * 64 + col], Eacc[i][j][r]);
      }
    }
}

// ---------------------------------------------------------------------------
// Fused layer3+layer4. Block = 64 rows x 128 decoded cols (grid 4x128=512).
// Per HID-chunk c: Tc = tanh(Et @ W3p-chunk + b3) [K=64], Dacc += Tc @ W4p
// chunk [K=64]. T never touches global memory (recomputed per n-block, x4).
// ---------------------------------------------------------------------------
__global__ __launch_bounds__(256)
void gemm34(const u16* __restrict__ Ebf, const u16* __restrict__ W3p,
            const float* __restrict__ b3, const u16* __restrict__ W4p,
            const float* __restrict__ b4, float* __restrict__ out)
{
  __shared__ u16 Et[64 * 66];         // 8.25 KB
  __shared__ u16 Tc[64 * 66];
  __shared__ u16 lW3[8 * 512];        // 8 KB
  __shared__ u16 lW4[16 * 512];       // 16 KB

  const int tid  = threadIdx.x;
  const int wave = tid >> 6;
  const int lane = tid & 63;
  const int quad = lane >> 4;
  const int l15  = lane & 15;
  const int wm = wave >> 1, wn = wave & 1;
  const int xslot = (l15 >> 1) & 3;

  const int m0 = blockIdx.y * 64;
  const int n0 = blockIdx.x * 128;

#pragma unroll
  for (int h = 0; h < 2; ++h) {       // Et <- Ebf tile (b128 copies)
    const int id = tid + h * 256;
    const int row = id >> 3, ch = id & 7;
    *(short8*)(Et + row * 66 + ch * 8) =
        *(const short8*)(Ebf + (size_t)(m0 + row) * 64 + ch * 8);
  }

  floatx4 Dacc[2][4];
#pragma unroll
  for (int i = 0; i < 2; ++i)
#pragma unroll
    for (int j = 0; j < 4; ++j) Dacc[i][j] = (floatx4){0.f, 0.f, 0.f, 0.f};

  for (int c = 0; c < 16; ++c) {
    __syncthreads();                  // Et ready (c=0) / prev Tc+lW reads done
#pragma unroll
    for (int u = 0; u < 2; ++u) {     // stage 8 W3p tiles
      const int t = wave + u * 4;
      load_lds16(W3p + (size_t)((c * 4 + (t >> 1)) * 2 + (t & 1)) * 512 + lane * 8,
                 lW3 + t * 512);
    }
    __syncthreads();

    floatx4 Tacc[2][2];
#pragma unroll
    for (int i = 0; i < 2; ++i)
#pragma unroll
      for (int j = 0; j < 2; ++j) Tacc[i][j] = (floatx4){0.f, 0.f, 0.f, 0.f};
#pragma unroll
    for (int kk = 0; kk < 2; ++kk) {
      short8 af[2];
#pragma unroll
      for (int i = 0; i < 2; ++i)
        af[i] = *(const short8*)(Et + (wm * 32 + i * 16 + l15) * 66 + kk * 32 + quad * 8);
#pragma unroll
      for (int j = 0; j < 2; ++j) {
        const short8 bf = *(const short8*)(lW3 + ((wn * 2 + j) * 2 + kk) * 512
                            + l15 * 32 + ((quad ^ xslot) << 3));
#pragma unroll
        for (int i = 0; i < 2; ++i)
          Tacc[i][j] = __builtin_amdgcn_mfma_f32_16x16x32_bf16(af[i], bf, Tacc[i][j], 0, 0, 0);
      }
    }
#pragma unroll
    for (int j = 0; j < 2; ++j) {
      const int col = wn * 32 + j * 16 + l15;
      const float bv = b3[c * 64 + col];
#pragma unroll
      for (int i = 0; i < 2; ++i)
#pragma unroll
        for (int r = 0; r < 4; ++r) {
          const int row = wm * 32 + i * 16 + quad * 4 + r;
          Tc[row * 66 + col] = f32_to_bf16(fast_tanh(Tacc[i][j][r] + bv));
        }
    }
#pragma unroll
    for (int u = 0; u < 4; ++u) {     // stage 16 W4p tiles
      const int t = wave + u * 4;
      load_lds16(W4p + (size_t)(((n0 >> 4) + (t >> 1)) * 32 + c * 2 + (t & 1)) * 512 + lane * 8,
                 lW4 + t * 512);
    }
    __syncthreads();                  // Tc visible + lW4 ready

#pragma unroll
    for (int kk = 0; kk < 2; ++kk) {
      short8 af[2];
#pragma unroll
      for (int i = 0; i < 2; ++i)
        af[i] = *(const short8*)(Tc + (wm * 32 + i * 16 + l15) * 66 + kk * 32 + quad * 8);
#pragma unroll
      for (int jj = 0; jj < 4; ++jj) {
        const short8 bf = *(const short8*)(lW4 + ((wn * 4 + jj) * 2 + kk) * 512
                            + l15 * 32 + ((quad ^ xslot) << 3));
#pragma unroll
        for (int i = 0; i < 2; ++i)
          Dacc[i][jj] = __builtin_amdgcn_mfma_f32_16x16x32_bf16(af[i], bf, Dacc[i][jj], 0, 0, 0);
      }
    }
  }

#pragma unroll
  for (int i = 0; i < 2; ++i)
#pragma unroll
    for (int jj = 0; jj < 4; ++jj) {
      const int col = n0 + wn * 64 + jj * 16 + l15;
      const float bv = b4[col];
#pragma unroll
      for (int r = 0; r < 4; ++r) {
        const int row = m0 + wm * 32 + i * 16 + quad * 4 + r;
        out[(size_t)row * 512 + col] = Dacc[i][jj][r] + bv;
      }
    }
}

// labels + class histogram
__global__ __launch_bounds__(256)
void labels_kernel(const float* __restrict__ x, int* __restrict__ labels,
                   int* __restrict__ counts)
{
  const int g = blockIdx.x * 256 + threadIdx.x;
  if (g < NROWS) {
    const int l = (int)x[(size_t)g * 513];
    labels[g] = l;
    atomicAdd(&counts[l], 1);
  }
}

__global__ void make_offsets(const int* __restrict__ counts,
                             int* __restrict__ offs, int* __restrict__ cursors)
{
  if (threadIdx.x == 0) {
    int s = 0;
    for (int c = 0; c < NCLS; ++c) { offs[c] = s; cursors[c] = s; s += counts[c]; }
    offs[NCLS] = s;
  }
}

__global__ __launch_bounds__(256)
void scatter_idx(const int* __restrict__ labels, int* __restrict__ cursors,
                 int* __restrict__ idx)
{
  const int i = blockIdx.x * 256 + threadIdx.x;
  if (i < NROWS) {
    const int c = labels[i];
    const int p = atomicAdd(&cursors[c], 1);
    idx[p] = i;
  }
}

// ---------------------------------------------------------------------------
// Ef (+b2) -> Ebf, plus per-row sq norm + per-class sums, one pass.
// 64 blocks x 4 waves x 32 rows; lane = col (coalesced). Stats use the
// bf16-rounded value (exactly consistent with the gram => diagonal D = 0).
// ---------------------------------------------------------------------------
__global__ __launch_bounds__(256)
void stats_sq(const float* __restrict__ Ef, const float* __restrict__ b2,
              const int* __restrict__ labels, u16* __restrict__ Ebf,
              float* __restrict__ sqrow, float* __restrict__ vsum,
              float* __restrict__ Ssum)
{
  __shared__ float lv[NCLS][64];
  __shared__ float lsq[NCLS][64];
  const int tid = threadIdx.x;
  for (int i = tid; i < NCLS * 64; i += 256) {
    ((float*)lv)[i] = 0.f; ((float*)lsq)[i] = 0.f;
  }
  __syncthreads();

  const int wave = tid >> 6, lane = tid & 63;
  const float bv = b2[lane];
  const int base = blockIdx.x * 128 + wave * 32;
  for (int r = 0; r < 32; ++r) {
    const int row = base + r;
    const int c = labels[row];
    const u16 h = f32_to_bf16(Ef[(size_t)row * 64 + lane] + bv);
    Ebf[(size_t)row * 64 + lane] = h;
    float v = bf16_to_f32(h);
    if (lane < 2) v = 0.f;
    const float v2 = v * v;
    atomicAdd(&lv[c][lane], v);
    atomicAdd(&lsq[c][lane], v2);
    float s = v2;
    for (int o = 32; o > 0; o >>= 1) s += __shfl_xor(s, o);
    if (lane == 0) sqrow[row] = s;
  }
  __syncthreads();

  for (int i = tid; i < NCLS * 64; i += 256) {
    const int c = i >> 6, k = i & 63;
    if (k >= 2) atomicAdd(&vsum[c * NCONS + k - 2], lv[c][k]);
  }
  if (tid < NCLS) {
    float s = 0.f;
    for (int k = 0; k < 64; ++k) s += lsq[tid][k];
    atomicAdd(&Ssum[tid], s);
  }
}

// ---------------------------------------------------------------------------
// Same-class pairwise hinge via bf16 MFMA gram (verified numerics since R2).
// LDS pitch 66 (odd dword stride) -> 2-way bank aliasing only.
// ---------------------------------------------------------------------------
__global__ __launch_bounds__(256)
void pairwise_mfma(const u16* __restrict__ Ebf, const float* __restrict__ sqrow,
                   const int* __restrict__ idx, const int* __restrict__ offs,
                   float* __restrict__ pair_sum)
{
  const int cls = blockIdx.y;
  int p = blockIdx.x, ti = 0, cnt = 16;
  while (p >= cnt) { p -= cnt; ++ti; --cnt; }   // block-uniform scalar decode
  const int tj = ti + p;

  const int start = offs[cls];
  const int n = offs[cls + 1] - start;
  if (ti * 64 >= n || tj * 64 >= n) return;

  constexpr int LDA = 66;
  __shared__ u16 Li[64 * LDA];
  __shared__ u16 Lj[64 * LDA];
  __shared__ float sqI[64], sqJ[64];

  const int tid = threadIdx.x;
  for (int e = tid; e < 1024; e += 256) {
    const int t = e >> 9;
    const int row = (e >> 3) & 63;
    const int ch = e & 7;
    const int g = (t ? tj : ti) * 64 + row;
    short8 v = (short8)0;
    if (g < n) {
      v = *(const short8*)(Ebf + (size_t)idx[start + g] * EMBN + ch * 8);
      if (ch == 0) { v[0] = 0; v[1] = 0; }
    }
    *(short8*)((t ? Lj : Li) + row * LDA + ch * 8) = v;
  }
  if (tid < 128) {
    const int t = tid >> 6, row = tid & 63;
    const int g = (t ? tj : ti) * 64 + row;
    (t ? sqJ : sqI)[row] = (g < n) ? sqrow[idx[start + g]] : 0.f;
  }
  __syncthreads();

  const int wave = tid >> 6, lane = tid & 63;
  const int wm = wave >> 1, wn = wave & 1;
  const int quad = lane >> 4, l15 = lane & 15;

  floatx4 acc[2][2];
#pragma unroll
  for (int i = 0; i < 2; ++i)
#pragma unroll
    for (int j = 0; j < 2; ++j) acc[i][j] = (floatx4){0.f, 0.f, 0.f, 0.f};

#pragma unroll
  for (int ks = 0; ks < 2; ++ks) {
    short8 af[2], bf[2];
#pragma unroll
    for (int i = 0; i < 2; ++i)
      af[i] = *(const short8*)(Li + (wm * 32 + i * 16 + l15) * LDA + ks * 32 + quad * 8);
#pragma unroll
    for (int j = 0; j < 2; ++j)
      bf[j] = *(const short8*)(Lj + (wn * 32 + j * 16 + l15) * LDA + ks * 32 + quad * 8);
#pragma unroll
    for (int i = 0; i < 2; ++i)
#pragma unroll
      for (int j = 0; j < 2; ++j)
        acc[i][j] = __builtin_amdgcn_mfma_f32_16x16x32_bf16(af[i], bf[j], acc[i][j], 0, 0, 0);
  }

  float local = 0.f;
#pragma unroll
  for (int i = 0; i < 2; ++i)
#pragma unroll
    for (int j = 0; j < 2; ++j)
#pragma unroll
      for (int r = 0; r < 4; ++r) {
        const int row = wm * 32 + i * 16 + quad * 4 + r;
        const int col = wn * 32 + j * 16 + l15;
        const int gi = ti * 64 + row, gj = tj * 64 + col;
        if (gi < n && gj < n && gi != gj) {
          const float D = (sqI[row] + sqJ[col] - 2.f * acc[i][j][r]) * (1.f / 62.f);
          local += fmaxf(0.f, MARGINF - D);
        }
      }
  if (ti < tj) local *= 2.f;

  __shared__ float red[256];
  red[tid] = local;
  __syncthreads();
  for (int st = 128; st > 0; st >>= 1) {
    if (tid < st) red[tid] += red[tid + st];
    __syncthreads();
  }
  if (tid == 0) atomicAdd(pair_sum, red[0]);
}

__device__ __forceinline__ double block_reduce_d(double v, double* red, int tid) {
  red[tid] = v;
  __syncthreads();
  for (int st = 128; st > 0; st >>= 1) {
    if (tid < st) red[tid] += red[tid + st];
    __syncthreads();
  }
  const double r = red[0];
  __syncthreads();
  return r;
}

// C_sim (factored, no N^2) and C_diff from pair_sum + analytic diagonal.
__global__ __launch_bounds__(256)
void finalize(const float* __restrict__ vsum, const float* __restrict__ Ssum,
              const int* __restrict__ counts, const float* __restrict__ pair_sum,
              float* __restrict__ out2)
{
  const int tid = threadIdx.x;
  __shared__ double red[256];

  double v = 0.0;
  if (tid < NCLS) v = (double)Ssum[tid] * (double)(NROWS - counts[tid]);
  const double t1 = block_reduce_d(v, red, tid);            // sum_c S_c (N - n_c)

  v = 0.0;
  if (tid < NCLS) { const double nc = (double)counts[tid]; v = nc * nc; }
  const double n_same = block_reduce_d(v, red, tid);        // sum n_c^2

  v = 0.0;
  for (int i = tid; i < NCLS * NCONS; i += 256) { const double w = vsum[i]; v += w * w; }
  const double t2 = block_reduce_d(v, red, tid);            // sum_c |v_c|^2

  v = 0.0;
  if (tid < NCONS) {
    double Vk = 0.0;
    for (int c = 0; c < NCLS; ++c) Vk += (double)vsum[c * NCONS + tid];
    v = Vk * Vk;
  }
  const double t3 = block_reduce_d(v, red, tid);            // |V|^2

  if (tid == 0) {
    const double n_diff = (double)NROWS * (double)NROWS - n_same;
    const double sim = 2.0 * t1 - 2.0 * (t3 - t2);
    const double C_sim = sim / 62.0 / (n_diff + 1.0);
    const double C_diff = ((double)pair_sum[0] + (double)NROWS * (double)MARGINF)
                          / (n_same + 1.0);
    out2[0] = (float)C_sim;
    out2[1] = (float)C_diff;
  }
}

// ---------------------------------------------------------------------------
// Workspace: 11.24 MB peak (proven-safe envelope). A0p [0,8MB) is dead after
// gemm12 and is overlaid by W4p (+0), W3p (+1MB), Ebf (+2MB) — pack2 and
// stats_sq run after gemm12 in stream order.
// ---------------------------------------------------------------------------
extern "C" void kernel_launch(void* const* d_in, const int* in_sizes, int n_in,
                              void* d_out, int out_size, void* d_ws, size_t ws_size,
                              hipStream_t stream)
{
  const float* x  = (const float*)d_in[0];
  const float* W1 = (const float*)d_in[1];
  const float* b1 = (const float*)d_in[2];
  const float* W2 = (const float*)d_in[3];
  const float* b2 = (const float*)d_in[4];
  const float* W3 = (const float*)d_in[5];
  const float* b3 = (const float*)d_in[6];
  const float* W4 = (const float*)d_in[7];
  const float* b4 = (const float*)d_in[8];
  float* out = (float*)d_out;

  char* ws = (char*)d_ws;
  const size_t KB = 1024, MB = 1ull << 20;
  u16* A0p    = (u16*)(ws + 0);                    // 8 MB, dead after gemm12
  u16* W4p    = (u16*)(ws + 0);                    //   overlay: 1 MB
  u16* W3p    = (u16*)(ws + 1 * MB);               //   overlay: 128 KB
  u16* Ebf    = (u16*)(ws + 2 * MB);               //   overlay: 1 MB
  float* Ef   = (float*)(ws + 8 * MB);             // 2 MB fp32 (atomic target)
  u16* W1p    = (u16*)(ws + 10 * MB);              // 1 MB
  u16* W2p    = (u16*)(ws + 11 * MB);              // 128 KB
  int* labels = (int*)(ws + 11 * MB + 128 * KB);   // 32 KB
  int* idx    = (int*)(ws + 11 * MB + 160 * KB);   // 32 KB
  float* slab = (float*)(ws + 11 * MB + 192 * KB); // 16 KB (zeroed by pack1)
  int*   counts  = (int*)slab;                     // [0,16)
  int*   offs    = counts + 16;                    // [16,33)
  int*   cursors = counts + 64;                    // [64,80)
  float* Ssum    = (float*)(counts + 96);          // 16
  float* psum    = (float*)(counts + 128);         // 1
  float* vsum    = (float*)(counts + 256);         // 992
  float* sqrow = (float*)(ws + 11 * MB + 208 * KB);// 32 KB  -> ends 11.24 MB
  (void)in_sizes; (void)n_in; (void)out_size; (void)ws_size;

  pack1<<<dim3(288), dim3(256), 0, stream>>>(W1, W2, W1p, W2p, Ef, slab);
  conv_a0p<<<dim3(2048), dim3(256), 0, stream>>>(x, A0p);
  labels_kernel<<<dim3(32), dim3(256), 0, stream>>>(x, labels, counts);
  make_offsets<<<dim3(1), dim3(64), 0, stream>>>(counts, offs, cursors);
  scatter_idx<<<dim3(32), dim3(256), 0, stream>>>(labels, cursors, idx);

  gemm12<<<dim3(128, 4), dim3(256), 0, stream>>>(A0p, W1p, b1, W2p, Ef);
  pack2<<<dim3(288), dim3(256), 0, stream>>>(W4, W3, W4p, W3p);
  stats_sq<<<dim3(64), dim3(256), 0, stream>>>(Ef, b2, labels, Ebf, sqrow, vsum, Ssum);
  gemm34<<<dim3(4, 128), dim3(256), 0, stream>>>(Ebf, W3p, b3, W4p, b4, out);
  pairwise_mfma<<<dim3(136, 16), dim3(256), 0, stream>>>(Ebf, sqrow, idx, offs, psum);
  finalize<<<dim3(1), dim3(256), 0, stream>>>(vsum, Ssum, counts, psum,
                                              out + (size_t)NROWS * DIN);
}

// Round 6
// 218.782 us; speedup vs baseline: 2.1627x; 1.1385x over previous
//
#include <hip/hip_runtime.h>
#include <stdint.h>

// Problem constants
#define NROWS 8192
#define DIN   512
#define HIDN  1024
#define EMBN  64
#define NCONS 62      // EMB - N_EFF
#define NCLS  16
#define MARGINF 0.01f

typedef unsigned short u16;
typedef __attribute__((ext_vector_type(8))) short short8;   // 8 bf16 (4 VGPRs)
typedef __attribute__((ext_vector_type(4))) float floatx4;  // 4 fp32 acc

__device__ __forceinline__ u16 f32_to_bf16(float f) {
  union { float f; uint32_t u; } x; x.f = f;
  uint32_t u = x.u;
  uint32_t r = (u + 0x7FFFu + ((u >> 16) & 1u)) >> 16;  // RNE
  return (u16)r;
}

__device__ __forceinline__ float bf16_to_f32(u16 h) {
  union { uint32_t u; float f; } x; x.u = (uint32_t)h << 16;
  return x.f;
}

__device__ __forceinline__ float fast_tanh(float x) {
  float xc = fminf(fmaxf(x, -10.f), 10.f);     // clamp: avoid inf/inf
  float e = __expf(2.f * xc);
  return (e - 1.f) * __builtin_amdgcn_rcpf(e + 1.f);
}

__device__ __forceinline__ void load_lds16(const u16* g, u16* l) {
  __builtin_amdgcn_global_load_lds(
      (const __attribute__((address_space(1))) void*)g,
      (__attribute__((address_space(3))) void*)l, 16, 0, 0);
}

// ---------------------------------------------------------------------------
// Weight pre-pack: W (K x N fp32) -> 1KB tiles [nt][ku], tile = 16 n-rows x
// 32 k. Row r's k-chunk c (8 bf16 = 16B) stored at slot c ^ ((r>>1)&3) so
// B-fragment ds_read_b128 after lane-ordered global_load_lds staging aliases
// banks at most 2-way (free, m136). Tile linear index = nt*KU + ku.
// ---------------------------------------------------------------------------
__device__ __forceinline__ void pack_tile(const float* __restrict__ W,
                                          u16* __restrict__ Wp,
                                          int N, int KU, int t, int lane)
{
  const int r = lane >> 2, slot = lane & 3;
  const int c = slot ^ ((r >> 1) & 3);
  const int nt = t / KU, ku = t - nt * KU;
  const int n = nt * 16 + r;
  const int kb = ku * 32 + c * 8;
  short8 v;
#pragma unroll
  for (int j = 0; j < 8; ++j) v[j] = (short)f32_to_bf16(W[(size_t)(kb + j) * N + n]);
  *(short8*)(Wp + ((size_t)t * 64 + lane) * 8) = v;
}

// ---------------------------------------------------------------------------
// One kernel for ALL independent prep (was 4 dispatches):
//   blocks [0,2048): x -> A0p (MFMA-A packed bf16) + zero Ef + labels (b<32)
//   [2048,2304): pack W1 (1024 tiles)   [2304,2336): pack W2 (128 tiles)
//   [2336,2368): pack W3 (128 tiles)    [2368,2624): pack W4 (1024 tiles)
//   [2624]: zero accumulator slab
// A0p tile (rt,ku): lane quad*16+l15 holds A[rt*16+l15][ku*32+quad*8 ..+8].
// ---------------------------------------------------------------------------
__global__ __launch_bounds__(256)
void prep_all(const float* __restrict__ x,
              const float* __restrict__ W1, const float* __restrict__ W2,
              const float* __restrict__ W3, const float* __restrict__ W4,
              u16* __restrict__ A0p, u16* __restrict__ W1p,
              u16* __restrict__ W2p, u16* __restrict__ W3p,
              u16* __restrict__ W4p, float* __restrict__ Ef,
              float* __restrict__ slab, int* __restrict__ labels)
{
  const int b = blockIdx.x;
  const int tid = threadIdx.x;
  const int tl = tid >> 6, lane = tid & 63;
  if (b < 2048) {
    Ef[b * 256 + tid] = 0.f;
    if (b < 32) {
      const int row = b * 256 + tid;
      labels[row] = (int)x[(size_t)row * 513];
    }
    const int t = b * 4 + tl;
    const int rt = t >> 4, ku = t & 15;
    const int r = lane & 15, q = lane >> 4;
    const float* src = x + (size_t)(rt * 16 + r) * 513 + 1 + ku * 32 + q * 8;
    short8 v;
#pragma unroll
    for (int j = 0; j < 8; ++j) v[j] = (short)f32_to_bf16(src[j]);
    *(short8*)(A0p + ((size_t)t * 64 + lane) * 8) = v;
  } else if (b < 2304) {
    pack_tile(W1, W1p, 1024, 16, (b - 2048) * 4 + tl, lane);
  } else if (b < 2336) {
    pack_tile(W2, W2p, 64, 32, (b - 2304) * 4 + tl, lane);
  } else if (b < 2368) {
    pack_tile(W3, W3p, 1024, 2, (b - 2336) * 4 + tl, lane);
  } else if (b < 2624) {
    pack_tile(W4, W4p, 512, 32, (b - 2368) * 4 + tl, lane);
  } else {
    for (int i = tid; i < 4096; i += 256) slab[i] = 0.f;
  }
}

// Histogram + prefix + counts in one tiny dispatch (slab pre-zero not needed).
__global__ __launch_bounds__(256)
void make_offsets(const int* __restrict__ labels, int* __restrict__ offs,
                  int* __restrict__ cursors, int* __restrict__ counts)
{
  __shared__ int h[NCLS];
  const int tid = threadIdx.x;
  if (tid < NCLS) h[tid] = 0;
  __syncthreads();
  for (int i = tid; i < NROWS; i += 256) atomicAdd(&h[labels[i]], 1);
  __syncthreads();
  if (tid == 0) {
    int s = 0;
    for (int c = 0; c < NCLS; ++c) { counts[c] = h[c]; offs[c] = s; cursors[c] = s; s += h[c]; }
    offs[NCLS] = s;
  }
}

__global__ __launch_bounds__(256)
void scatter_idx(const int* __restrict__ labels, int* __restrict__ cursors,
                 int* __restrict__ idx)
{
  const int i = blockIdx.x * 256 + threadIdx.x;
  if (i < NROWS) {
    const int c = labels[i];
    const int p = atomicAdd(&cursors[c], 1);
    idx[p] = i;
  }
}

// ---------------------------------------------------------------------------
// Fused layer1+layer2, HID split 4 ways (grid 128x4). Block = 64 rows x 256
// HID cols. Single-barrier double-buffered K-loop: stage step s+1 into
// lB[1-p] BEFORE computing from lB[p]; the end-of-iter barrier's vmcnt drain
// then overlaps 16 MFMAs of compute. E-phase: all 32 W2 tiles staged at once
// into the dead lB array concurrent with tanh+Hc write -> barrier-free
// es-loop. Partial E accumulated into fp32 Ef via atomicAdd (pre-zeroed).
// MFMA layouts (m89/m91): A[m=l15][k=quad*8+j]; B[k=quad*8+j][n=l15];
// C/D col=l15, row=quad*4+reg. 18 barriers total (was ~41).
// ---------------------------------------------------------------------------
__global__ __launch_bounds__(256)
void gemm12(const u16* __restrict__ A0p, const u16* __restrict__ W1p,
            const float* __restrict__ b1, const u16* __restrict__ W2p,
            float* __restrict__ Ef)
{
  __shared__ u16 lB[2][16 * 512];   // 32 KB dbuf; whole array reused as lW2
  __shared__ u16 Hc[4][64 * 66];    // 33 KB -> total 65 KB, 2 blocks/CU

  const int tid = threadIdx.x, wave = tid >> 6, lane = tid & 63;
  const int quad = lane >> 4, l15 = lane & 15;
  const int wm = wave >> 1, wn = wave & 1;
  const int xslot = (l15 >> 1) & 3;
  const int m0 = blockIdx.x * 64;
  const int g = blockIdx.y;

  floatx4 Hacc[4][2][2];
#pragma unroll
  for (int c = 0; c < 4; ++c)
#pragma unroll
    for (int i = 0; i < 2; ++i)
#pragma unroll
      for (int j = 0; j < 2; ++j) Hacc[c][i][j] = (floatx4){0.f, 0.f, 0.f, 0.f};

  // prologue: stage K-step 0
#pragma unroll
  for (int u = 0; u < 4; ++u) {
    const int jt = wave + u * 4;
    load_lds16(W1p + (size_t)((g * 16 + jt) * 16) * 512 + lane * 8, lB[0] + jt * 512);
  }
  __syncthreads();

  for (int s = 0; s < 16; ++s) {
    const int p = s & 1;
    if (s < 15) {
#pragma unroll
      for (int u = 0; u < 4; ++u) {   // stage s+1 (in flight during compute)
        const int jt = wave + u * 4;
        load_lds16(W1p + (size_t)((g * 16 + jt) * 16 + s + 1) * 512 + lane * 8,
                   lB[1 - p] + jt * 512);
      }
    }
    short8 af[2];
#pragma unroll
    for (int i = 0; i < 2; ++i)       // A-frags direct from packed global
      af[i] = *(const short8*)(A0p +
               (size_t)((blockIdx.x * 4 + wm * 2 + i) * 16 + s) * 512 + lane * 8);
#pragma unroll
    for (int c = 0; c < 4; ++c)
#pragma unroll
      for (int j = 0; j < 2; ++j) {
        const short8 bf = *(const short8*)(lB[p] + (c * 4 + wn * 2 + j) * 512
                              + l15 * 32 + ((quad ^ xslot) << 3));
#pragma unroll
        for (int i = 0; i < 2; ++i)
          Hacc[c][i][j] = __builtin_amdgcn_mfma_f32_16x16x32_bf16(af[i], bf, Hacc[c][i][j], 0, 0, 0);
      }
    __syncthreads();
  }

  // stage ALL 32 W2 tiles into lB (dead after K-loop); overlaps tanh below
  u16* lW2 = &lB[0][0];
#pragma unroll
  for (int u = 0; u < 8; ++u) {
    const int t = wave * 8 + u;       // t = nt*8 + kl
    load_lds16(W2p + (size_t)((t >> 3) * 32 + g * 8 + (t & 7)) * 512 + lane * 8,
               lW2 + t * 512);
  }
#pragma unroll
  for (int c = 0; c < 4; ++c)
#pragma unroll
    for (int j = 0; j < 2; ++j) {
      const int col = wn * 32 + j * 16 + l15;
      const float bv = b1[g * 256 + c * 64 + col];
#pragma unroll
      for (int i = 0; i < 2; ++i)
#pragma unroll
        for (int r = 0; r < 4; ++r)
          Hc[c][(wm * 32 + i * 16 + quad * 4 + r) * 66 + col] =
              f32_to_bf16(fast_tanh(Hacc[c][i][j][r] + bv));
    }
  __syncthreads();

  floatx4 Eacc[2][2];
#pragma unroll
  for (int i = 0; i < 2; ++i)
#pragma unroll
    for (int j = 0; j < 2; ++j) Eacc[i][j] = (floatx4){0.f, 0.f, 0.f, 0.f};

#pragma unroll
  for (int es = 0; es < 8; ++es) {    // barrier-free: pure LDS + MFMA
    const int cc = es >> 1, hh = es & 1;
    short8 af2[2];
#pragma unroll
    for (int i = 0; i < 2; ++i)
      af2[i] = *(const short8*)(Hc[cc] + (wm * 32 + i * 16 + l15) * 66 + hh * 32 + quad * 8);
#pragma unroll
    for (int j = 0; j < 2; ++j) {
      const short8 bf = *(const short8*)(lW2 + ((wn * 2 + j) * 8 + es) * 512
                            + l15 * 32 + ((quad ^ xslot) << 3));
#pragma unroll
      for (int i = 0; i < 2; ++i)
        Eacc[i][j] = __builtin_amdgcn_mfma_f32_16x16x32_bf16(af2[i], bf, Eacc[i][j], 0, 0, 0);
    }
  }

#pragma unroll
  for (int i = 0; i < 2; ++i)
#pragma unroll
    for (int j = 0; j < 2; ++j) {
      const int col = wn * 32 + j * 16 + l15;
#pragma unroll
      for (int r = 0; r < 4; ++r) {
        const int row = m0 + wm * 32 + i * 16 + quad * 4 + r;
        atomicAdd(&Ef[(size_t)row * 64 + col], Eacc[i][j][r]);
      }
    }
}

// ---------------------------------------------------------------------------
// Fused layer3+layer4, 4x1 wave-M tiling: wave owns 16 rows x all 128 cols,
// so the Tc C-layout->A-layout round-trip is WAVE-PRIVATE (compiler lgkmcnt,
// no barrier). Double-buffered lW3/lW4 staged at chunk top -> ONE barrier per
// chunk (17 total, was 48). T recomputed per n-block (x4, cheap MFMA).
// ---------------------------------------------------------------------------
__global__ __launch_bounds__(256)
void gemm34(const u16* __restrict__ Ebf, const u16* __restrict__ W3p,
            const float* __restrict__ b3, const u16* __restrict__ W4p,
            const float* __restrict__ b4, float* __restrict__ out)
{
  __shared__ u16 Et[64 * 66];         // 8.25 KB
  __shared__ u16 Tc[64 * 66];         // 8.25 KB (wave-private 16-row bands)
  __shared__ u16 lW3[2][8 * 512];     // 16 KB
  __shared__ u16 lW4[2][16 * 512];    // 32 KB -> 64.5 KB, 2 blocks/CU

  const int tid = threadIdx.x, wave = tid >> 6, lane = tid & 63;
  const int quad = lane >> 4, l15 = lane & 15;
  const int xslot = (l15 >> 1) & 3;
  const int m0 = blockIdx.y * 64;
  const int n0 = blockIdx.x * 128;

#pragma unroll
  for (int h = 0; h < 2; ++h) {       // Et <- Ebf tile
    const int id = tid + h * 256;
    const int row = id >> 3, ch = id & 7;
    *(short8*)(Et + row * 66 + ch * 8) =
        *(const short8*)(Ebf + (size_t)(m0 + row) * 64 + ch * 8);
  }
  // prologue: stage chunk 0
#pragma unroll
  for (int u = 0; u < 2; ++u) {
    const int t = wave + u * 4;
    load_lds16(W3p + (size_t)t * 512 + lane * 8, lW3[0] + t * 512);
  }
#pragma unroll
  for (int u = 0; u < 4; ++u) {
    const int t = wave + u * 4;
    load_lds16(W4p + (size_t)(((n0 >> 4) + (t >> 1)) * 32 + (t & 1)) * 512 + lane * 8,
               lW4[0] + t * 512);
  }
  __syncthreads();

  floatx4 Dacc[8];
#pragma unroll
  for (int jj = 0; jj < 8; ++jj) Dacc[jj] = (floatx4){0.f, 0.f, 0.f, 0.f};

  for (int c = 0; c < 16; ++c) {
    const int p = c & 1;
    if (c < 15) {                     // stage chunk c+1 (overlaps T+D compute)
#pragma unroll
      for (int u = 0; u < 2; ++u) {
        const int t = wave + u * 4;
        load_lds16(W3p + (size_t)(((c + 1) * 4 + (t >> 1)) * 2 + (t & 1)) * 512 + lane * 8,
                   lW3[1 - p] + t * 512);
      }
#pragma unroll
      for (int u = 0; u < 4; ++u) {
        const int t = wave + u * 4;
        load_lds16(W4p + (size_t)(((n0 >> 4) + (t >> 1)) * 32 + (c + 1) * 2 + (t & 1)) * 512 + lane * 8,
                   lW4[1 - p] + t * 512);
      }
    }
    // T phase: rows wave*16..+16 (wave-private)
    floatx4 Tacc[4];
#pragma unroll
    for (int j = 0; j < 4; ++j) Tacc[j] = (floatx4){0.f, 0.f, 0.f, 0.f};
#pragma unroll
    for (int kk = 0; kk < 2; ++kk) {
      const short8 af = *(const short8*)(Et + (wave * 16 + l15) * 66 + kk * 32 + quad * 8);
#pragma unroll
      for (int j = 0; j < 4; ++j) {
        const short8 bf = *(const short8*)(lW3[p] + (j * 2 + kk) * 512
                              + l15 * 32 + ((quad ^ xslot) << 3));
        Tacc[j] = __builtin_amdgcn_mfma_f32_16x16x32_bf16(af, bf, Tacc[j], 0, 0, 0);
      }
    }
#pragma unroll
    for (int j = 0; j < 4; ++j) {
      const int col = j * 16 + l15;
      const float bv = b3[c * 64 + col];
#pragma unroll
      for (int r = 0; r < 4; ++r)
        Tc[(wave * 16 + quad * 4 + r) * 66 + col] = f32_to_bf16(fast_tanh(Tacc[j][r] + bv));
    }
    // D phase: same-wave ds_write->ds_read dependency only
#pragma unroll
    for (int kk = 0; kk < 2; ++kk) {
      const short8 af = *(const short8*)(Tc + (wave * 16 + l15) * 66 + kk * 32 + quad * 8);
#pragma unroll
      for (int jj = 0; jj < 8; ++jj) {
        const short8 bf = *(const short8*)(lW4[p] + (jj * 2 + kk) * 512
                              + l15 * 32 + ((quad ^ xslot) << 3));
        Dacc[jj] = __builtin_amdgcn_mfma_f32_16x16x32_bf16(af, bf, Dacc[jj], 0, 0, 0);
      }
    }
    __syncthreads();                  // protects lW3/lW4[p] + Tc for next chunk
  }

#pragma unroll
  for (int jj = 0; jj < 8; ++jj) {
    const int col = n0 + jj * 16 + l15;
    const float bv = b4[col];
#pragma unroll
    for (int r = 0; r < 4; ++r) {
      const int row = m0 + wave * 16 + quad * 4 + r;
      out[(size_t)row * 512 + col] = Dacc[jj][r] + bv;
    }
  }
}

// ---------------------------------------------------------------------------
// Ef (+b2) -> Ebf, per-row sq norm + per-class sums, one pass. 128 blocks x
// 4 waves x 16 rows; lane = col (coalesced). Stats use the bf16-rounded value
// (exactly consistent with the gram => diagonal D = 0).
// ---------------------------------------------------------------------------
__global__ __launch_bounds__(256)
void stats_sq(const float* __restrict__ Ef, const float* __restrict__ b2,
              const int* __restrict__ labels, u16* __restrict__ Ebf,
              float* __restrict__ sqrow, float* __restrict__ vsum,
              float* __restrict__ Ssum)
{
  __shared__ float lv[NCLS][64];
  __shared__ float lsq[NCLS][64];
  const int tid = threadIdx.x;
  for (int i = tid; i < NCLS * 64; i += 256) {
    ((float*)lv)[i] = 0.f; ((float*)lsq)[i] = 0.f;
  }
  __syncthreads();

  const int wave = tid >> 6, lane = tid & 63;
  const float bv = b2[lane];
  const int base = blockIdx.x * 64 + wave * 16;
  for (int r = 0; r < 16; ++r) {
    const int row = base + r;
    const int c = labels[row];
    const u16 h = f32_to_bf16(Ef[(size_t)row * 64 + lane] + bv);
    Ebf[(size_t)row * 64 + lane] = h;
    float v = bf16_to_f32(h);
    if (lane < 2) v = 0.f;
    const float v2 = v * v;
    atomicAdd(&lv[c][lane], v);
    atomicAdd(&lsq[c][lane], v2);
    float s = v2;
    for (int o = 32; o > 0; o >>= 1) s += __shfl_xor(s, o);
    if (lane == 0) sqrow[row] = s;
  }
  __syncthreads();

  for (int i = tid; i < NCLS * 64; i += 256) {
    const int c = i >> 6, k = i & 63;
    if (k >= 2) atomicAdd(&vsum[c * NCONS + k - 2], lv[c][k]);
  }
  if (tid < NCLS) {
    float s = 0.f;
    for (int k = 0; k < 64; ++k) s += lsq[tid][k];
    atomicAdd(&Ssum[tid], s);
  }
}

// ---------------------------------------------------------------------------
// Same-class pairwise hinge via bf16 MFMA gram (verified numerics since R2).
// ---------------------------------------------------------------------------
__global__ __launch_bounds__(256)
void pairwise_mfma(const u16* __restrict__ Ebf, const float* __restrict__ sqrow,
                   const int* __restrict__ idx, const int* __restrict__ offs,
                   float* __restrict__ pair_sum)
{
  const int cls = blockIdx.y;
  int p = blockIdx.x, ti = 0, cnt = 16;
  while (p >= cnt) { p -= cnt; ++ti; --cnt; }   // block-uniform scalar decode
  const int tj = ti + p;

  const int start = offs[cls];
  const int n = offs[cls + 1] - start;
  if (ti * 64 >= n || tj * 64 >= n) return;

  constexpr int LDA = 66;
  __shared__ u16 Li[64 * LDA];
  __shared__ u16 Lj[64 * LDA];
  __shared__ float sqI[64], sqJ[64];

  const int tid = threadIdx.x;
  for (int e = tid; e < 1024; e += 256) {
    const int t = e >> 9;
    const int row = (e >> 3) & 63;
    const int ch = e & 7;
    const int g = (t ? tj : ti) * 64 + row;
    short8 v = (short8)0;
    if (g < n) {
      v = *(const short8*)(Ebf + (size_t)idx[start + g] * EMBN + ch * 8);
      if (ch == 0) { v[0] = 0; v[1] = 0; }
    }
    *(short8*)((t ? Lj : Li) + row * LDA + ch * 8) = v;
  }
  if (tid < 128) {
    const int t = tid >> 6, row = tid & 63;
    const int g = (t ? tj : ti) * 64 + row;
    (t ? sqJ : sqI)[row] = (g < n) ? sqrow[idx[start + g]] : 0.f;
  }
  __syncthreads();

  const int wave = tid >> 6, lane = tid & 63;
  const int wm = wave >> 1, wn = wave & 1;
  const int quad = lane >> 4, l15 = lane & 15;

  floatx4 acc[2][2];
#pragma unroll
  for (int i = 0; i < 2; ++i)
#pragma unroll
    for (int j = 0; j < 2; ++j) acc[i][j] = (floatx4){0.f, 0.f, 0.f, 0.f};

#pragma unroll
  for (int ks = 0; ks < 2; ++ks) {
    short8 af[2], bf[2];
#pragma unroll
    for (int i = 0; i < 2; ++i)
      af[i] = *(const short8*)(Li + (wm * 32 + i * 16 + l15) * LDA + ks * 32 + quad * 8);
#pragma unroll
    for (int j = 0; j < 2; ++j)
      bf[j] = *(const short8*)(Lj + (wn * 32 + j * 16 + l15) * LDA + ks * 32 + quad * 8);
#pragma unroll
    for (int i = 0; i < 2; ++i)
#pragma unroll
      for (int j = 0; j < 2; ++j)
        acc[i][j] = __builtin_amdgcn_mfma_f32_16x16x32_bf16(af[i], bf[j], acc[i][j], 0, 0, 0);
  }

  float local = 0.f;
#pragma unroll
  for (int i = 0; i < 2; ++i)
#pragma unroll
    for (int j = 0; j < 2; ++j)
#pragma unroll
      for (int r = 0; r < 4; ++r) {
        const int row = wm * 32 + i * 16 + quad * 4 + r;
        const int col = wn * 32 + j * 16 + l15;
        const int gi = ti * 64 + row, gj = tj * 64 + col;
        if (gi < n && gj < n && gi != gj) {
          const float D = (sqI[row] + sqJ[col] - 2.f * acc[i][j][r]) * (1.f / 62.f);
          local += fmaxf(0.f, MARGINF - D);
        }
      }
  if (ti < tj) local *= 2.f;

  __shared__ float red[256];
  red[tid] = local;
  __syncthreads();
  for (int st = 128; st > 0; st >>= 1) {
    if (tid < st) red[tid] += red[tid + st];
    __syncthreads();
  }
  if (tid == 0) atomicAdd(pair_sum, red[0]);
}

__device__ __forceinline__ double block_reduce_d(double v, double* red, int tid) {
  red[tid] = v;
  __syncthreads();
  for (int st = 128; st > 0; st >>= 1) {
    if (tid < st) red[tid] += red[tid + st];
    __syncthreads();
  }
  const double r = red[0];
  __syncthreads();
  return r;
}

// C_sim (factored, no N^2) and C_diff from pair_sum + analytic diagonal.
__global__ __launch_bounds__(256)
void finalize(const float* __restrict__ vsum, const float* __restrict__ Ssum,
              const int* __restrict__ counts, const float* __restrict__ pair_sum,
              float* __restrict__ out2)
{
  const int tid = threadIdx.x;
  __shared__ double red[256];

  double v = 0.0;
  if (tid < NCLS) v = (double)Ssum[tid] * (double)(NROWS - counts[tid]);
  const double t1 = block_reduce_d(v, red, tid);            // sum_c S_c (N - n_c)

  v = 0.0;
  if (tid < NCLS) { const double nc = (double)counts[tid]; v = nc * nc; }
  const double n_same = block_reduce_d(v, red, tid);        // sum n_c^2

  v = 0.0;
  for (int i = tid; i < NCLS * NCONS; i += 256) { const double w = vsum[i]; v += w * w; }
  const double t2 = block_reduce_d(v, red, tid);            // sum_c |v_c|^2

  v = 0.0;
  if (tid < NCONS) {
    double Vk = 0.0;
    for (int c = 0; c < NCLS; ++c) Vk += (double)vsum[c * NCONS + tid];
    v = Vk * Vk;
  }
  const double t3 = block_reduce_d(v, red, tid);            // |V|^2

  if (tid == 0) {
    const double n_diff = (double)NROWS * (double)NROWS - n_same;
    const double sim = 2.0 * t1 - 2.0 * (t3 - t2);
    const double C_sim = sim / 62.0 / (n_diff + 1.0);
    const double C_diff = ((double)pair_sum[0] + (double)NROWS * (double)MARGINF)
                          / (n_same + 1.0);
    out2[0] = (float)C_sim;
    out2[1] = (float)C_diff;
  }
}

// ---------------------------------------------------------------------------
// ws_size is ~256 MB (revealed by the harness's 0xAA fill in the R5 profile);
// footprint here is a flat 13.4 MB, no overlays. 8 dispatches (was 11).
// ---------------------------------------------------------------------------
extern "C" void kernel_launch(void* const* d_in, const int* in_sizes, int n_in,
                              void* d_out, int out_size, void* d_ws, size_t ws_size,
                              hipStream_t stream)
{
  const float* x  = (const float*)d_in[0];
  const float* W1 = (const float*)d_in[1];
  const float* b1 = (const float*)d_in[2];
  const float* W2 = (const float*)d_in[3];
  const float* b2 = (const float*)d_in[4];
  const float* W3 = (const float*)d_in[5];
  const float* b3 = (const float*)d_in[6];
  const float* W4 = (const float*)d_in[7];
  const float* b4 = (const float*)d_in[8];
  float* out = (float*)d_out;

  char* ws = (char*)d_ws;
  const size_t KB = 1024, MB = 1ull << 20;
  u16* A0p    = (u16*)(ws + 0);                    // 8 MB packed A
  u16* W1p    = (u16*)(ws + 8 * MB);               // 1 MB
  u16* W2p    = (u16*)(ws + 9 * MB);               // 128 KB
  u16* W3p    = (u16*)(ws + 9 * MB + 128 * KB);    // 128 KB
  u16* W4p    = (u16*)(ws + 9 * MB + 256 * KB);    // 1 MB
  float* Ef   = (float*)(ws + 10 * MB + 256 * KB); // 2 MB fp32 (atomic target)
  u16* Ebf    = (u16*)(ws + 12 * MB + 256 * KB);   // 1 MB
  int* labels = (int*)(ws + 13 * MB + 256 * KB);   // 32 KB
  int* idx    = (int*)(ws + 13 * MB + 288 * KB);   // 32 KB
  float* slab = (float*)(ws + 13 * MB + 320 * KB); // 16 KB (zeroed in prep_all)
  int*   counts  = (int*)slab;                     // [0,16)
  int*   offs    = counts + 16;                    // [16,33)
  int*   cursors = counts + 64;                    // [64,80)
  float* Ssum    = (float*)(counts + 96);          // 16
  float* psum    = (float*)(counts + 128);         // 1
  float* vsum    = (float*)(counts + 256);         // 992
  float* sqrow = (float*)(ws + 13 * MB + 336 * KB);// 32 KB -> ends 13.36 MB
  (void)in_sizes; (void)n_in; (void)out_size; (void)ws_size;

  prep_all<<<dim3(2625), dim3(256), 0, stream>>>(x, W1, W2, W3, W4,
                                                 A0p, W1p, W2p, W3p, W4p,
                                                 Ef, slab, labels);
  make_offsets<<<dim3(1), dim3(256), 0, stream>>>(labels, offs, cursors, counts);
  scatter_idx<<<dim3(32), dim3(256), 0, stream>>>(labels, cursors, idx);

  gemm12<<<dim3(128, 4), dim3(256), 0, stream>>>(A0p, W1p, b1, W2p, Ef);
  stats_sq<<<dim3(128), dim3(256), 0, stream>>>(Ef, b2, labels, Ebf, sqrow, vsum, Ssum);
  gemm34<<<dim3(4, 128), dim3(256), 0, stream>>>(Ebf, W3p, b3, W4p, b4, out);
  pairwise_mfma<<<dim3(136, 16), dim3(256), 0, stream>>>(Ebf, sqrow, idx, offs, psum);
  finalize<<<dim3(1), dim3(256), 0, stream>>>(vsum, Ssum, counts, psum,
                                              out + (size_t)NROWS * DIN);
}